// Round 8
// baseline (187.824 us; speedup 1.0000x reference)
//
#include <hip/hip_runtime.h>
#include <stdint.h>

#define SCORE_THRESH 0.05f
#define IOU_THRESH 0.5f
#define TOP_K 1000
#define MAX_DET 100

#define D0_BITS 13
#define D0_BINS 8192           // 2^13
#define NREP 4                 // replicated pass-0 histograms (R7 showed 8 = no gain)
#define CAND_CAP 2048
#define NMS_CHUNK 128          // rows per NMS staging chunk (dbuf: 2x128x16 u64 = 32KB)

typedef unsigned int u32;
typedef unsigned long long u64;

// ---- ws layout (bytes) ----
// [hist0][hist1][state][bar] is one contiguous host-memset region.
#define OFF_HIST0    0          // u32[NREP*8192] = 131072
#define OFF_HIST1    131072     // u32[65536] = 262144 -> 393216
#define OFF_STATE    393216     // u32 slots, each padded to its own 128B line:
                                //   slot0=k_rem slot1=d0cut slot2=d1cut slot5=cand_cnt
#define OFF_BAR      394240     // 7 barriers x 2048B flag rows -> 408576
#define MEMSET_LEN   408576
#define OFF_CAND     408576     // u32[2048] -> 416768
#define OFF_RFLAG    416768     // u32[1000] -> 420768
#define OFF_SIDX     420768     // u32[1000] -> 424768
#define OFF_SSCORE   424768     // float[1000] -> 428768
#define OFF_CBOX     428768     // float[4000] -> 444768 (16B aligned)
#define OFF_M        444768     // u64[1000*16] = 128000 -> 572768 (8B aligned)
#define OFF_SCORES   572768     // float[A]

#define BAR_STRIDE_U32 512      // one u32 flag per block, 2KB row per barrier

__device__ __forceinline__ u32 order_f32(float f) {
    u32 b = __float_as_uint(f);
    return (b & 0x80000000u) ? ~b : (b | 0x80000000u);
}

// MALL-direct (sc1) accessors: relaxed agent-scope atomics carry no fence, so
// NO buffer_wbl2 / buffer_inv is ever emitted. Stores write through to the
// coherence point without allocating L1/L2; loads bypass stale caches.
__device__ __forceinline__ void st_sc(u32* p, u32 v)   { __hip_atomic_store(p, v, __ATOMIC_RELAXED, __HIP_MEMORY_SCOPE_AGENT); }
__device__ __forceinline__ void st_sc(float* p, float v){ __hip_atomic_store(p, v, __ATOMIC_RELAXED, __HIP_MEMORY_SCOPE_AGENT); }
__device__ __forceinline__ void st_sc(u64* p, u64 v)   { __hip_atomic_store(p, v, __ATOMIC_RELAXED, __HIP_MEMORY_SCOPE_AGENT); }
__device__ __forceinline__ u32  ld_sc(u32* p)          { return __hip_atomic_load(p, __ATOMIC_RELAXED, __HIP_MEMORY_SCOPE_AGENT); }

// Device-wide barrier v4: FLAG ARRAY, zero RMWs, zero cache-maintenance.
// R1: acquire-spin (buffer_inv/poll) -> 620us. R2: release/acquire per
// block-barrier (wbl2+inv tag-walks) -> 271us. R3-R7: counter-tree -> ~98us,
// insensitive to NREP / wake path / NMS chain  => last untested sync cost is
// ARRIVAL fan-in: 64 same-address fetch_adds per group serialize at the
// memory-side ALU (~2-2.5us/barrier). v4: arrival = ONE sc1 store to the
// block's own flag word (fully parallel); every waiter sweeps all G flags
// (2 loads/thread, wave-parallel) and reduces with __syncthreads_and.
// Correctness: __syncthreads at arrival drains every wave's vmcnt (HIP
// barrier semantics) -> all this block's sc1 data stores are at the
// coherence point before the flag store issues. Readers first-touch data
// lines only after the producing barrier (layout discipline, unchanged).
// Flags are per-barrier rows, monotone 0->1, host-zeroed: skipped waits legal.
__device__ __forceinline__ void gbar(u32* barr, int k, int b, int G, bool dowait) {
    __syncthreads();                      // drains all waves' vmcnt
    u32* f = barr + (size_t)k * BAR_STRIDE_U32;
    if (threadIdx.x == 0) st_sc(&f[b], 1u);
    if (dowait) {
        for (;;) {
            int my = 1;
            for (int i = (int)threadIdx.x; i < G; i += 256) my &= (int)ld_sc(&f[i]);
            if (__syncthreads_and(my)) break;
            __builtin_amdgcn_s_sleep(8);
        }
        asm volatile("" ::: "memory");
    }
}

union ShMem {
    u32 hl[D0_BINS / 2];                               // 16 KB — S1 LDS histogram (u16-packed)
    u32 wtot[4];                                       // S2/S4 wave totals
    struct { u32 wcnt[4]; u32 wbase[4]; u32 bbase; } cmp;  // S5 compact
    struct { u64 ckeys[8]; u32 wpart[4][8]; } rank;    // S6
    struct {
        u64 Ml[2 * NMS_CHUNK * 16];                    // 32 KB double-buffered mask chunks
        u64 keepS[16];
        u32 nib[256];
        int act[TOP_K];
        u32 wsum[4];
        int nactS;
        int det[MAX_DET];
    } nms;                                             // ~37.6 KB total (proven footprint)
};

__global__ void __launch_bounds__(256, 2)
mega(const float* __restrict__ cls, const float* __restrict__ regs,
     const float* __restrict__ anchors, const int* __restrict__ pH,
     const int* __restrict__ pW, int A, int C,
     char* __restrict__ ws, float* __restrict__ out)
{
    __shared__ ShMem sh;
    u32*   hist0  = (u32*)(ws + OFF_HIST0);
    u32*   hist1  = (u32*)(ws + OFF_HIST1);
    u32*   state  = (u32*)(ws + OFF_STATE);   // slot i at state[i*32] (own 128B line)
    u32*   barr   = (u32*)(ws + OFF_BAR);
    u32*   cand   = (u32*)(ws + OFF_CAND);
    u32*   rflag  = (u32*)(ws + OFF_RFLAG);
    u32*   sidx   = (u32*)(ws + OFF_SIDX);
    float* sscore = (float*)(ws + OFF_SSCORE);
    float* cbox   = (float*)(ws + OFF_CBOX);
    u64*   M      = (u64*)(ws + OFF_M);
    float* scores = (float*)(ws + OFF_SCORES);

    const int t = threadIdx.x;
    const int b = blockIdx.x;
    const int G = gridDim.x;
    const int gid = b * 256 + t;
    const int gstride = G * 256;
    const int lane = t & 63, wv = t >> 6;

    // ---------- S1: coalesced class-max + thresholded score + pass-0 hist ----------
    // hist0/hist1/state/bar were zeroed by the host memset (prior dispatch).
    if (C == 80) {
        for (int i = t; i < D0_BINS / 2; i += 256) sh.hl[i] = 0;
        __syncthreads();
        int sub = t & 3;           // which 20-float quarter of the 80 classes
        int la  = t >> 2;          // local anchor 0..63
        int nstrips = (A + 63) >> 6;
        int per = (nstrips + G - 1) / G;
        for (int s = 0; s < per; s++) {
            int a = (b * per + s) * 64 + la;
            float m = -1e30f;
            if (a < A) {
                const float* p = cls + (size_t)a * 80 + sub * 4;
                #pragma unroll
                for (int k2 = 0; k2 < 5; k2++) {
                    float4 v = *(const float4*)(p + k2 * 16);
                    m = fmaxf(m, fmaxf(fmaxf(v.x, v.y), fmaxf(v.z, v.w)));
                }
            }
            m = fmaxf(m, __shfl_xor(m, 1, 64));
            m = fmaxf(m, __shfl_xor(m, 2, 64));
            if (sub == 0 && a < A) {
                float s0 = (m > SCORE_THRESH) ? m : -1.0f;
                st_sc(&scores[a], s0);                  // sc1: visible at MALL
                u32 d = order_f32(s0) >> (32 - D0_BITS);
                atomicAdd(&sh.hl[d >> 1], (d & 1) ? 0x10000u : 1u);
            }
        }
        __syncthreads();
        u32* rep = hist0 + (size_t)(b & (NREP - 1)) * D0_BINS;
        for (int i = t; i < D0_BINS / 2; i += 256) {
            u32 v = sh.hl[i];
            if (v & 0xFFFFu) atomicAdd(&rep[2 * i],     v & 0xFFFFu);   // memory-side RMW
            if (v >> 16)     atomicAdd(&rep[2 * i + 1], v >> 16);
        }
    } else {
        u32* rep = hist0 + (size_t)(b & (NREP - 1)) * D0_BINS;
        for (int a = gid; a < A; a += gstride) {
            const float* p = cls + (size_t)a * C;
            float m = -1e30f;
            for (int c = 0; c < C; c++) m = fmaxf(m, p[c]);
            float s0 = (m > SCORE_THRESH) ? m : -1.0f;
            st_sc(&scores[a], s0);
            atomicAdd(&rep[order_f32(s0) >> (32 - D0_BITS)], 1u);
        }
    }
    // All blocks wait: after bar0, every block's scores are at the
    // coherence point -> the prefetch below is safe.
    gbar(barr, 0, b, G, true);

    // ---------- S2: scan0 (block 0) ∥ prefetch (blocks >0) ----------
    if (b == 0) {
        u32 cnt[32];
        #pragma unroll
        for (int i = 0; i < 32; i++) cnt[i] = 0;
        const uint4* hp = (const uint4*)hist0;
        #pragma unroll
        for (int r = 0; r < NREP; r++) {
            #pragma unroll
            for (int i = 0; i < 8; i++) {
                uint4 v = hp[r * (D0_BINS / 4) + t * 8 + i];
                cnt[4*i]   += v.x; cnt[4*i+1] += v.y;
                cnt[4*i+2] += v.z; cnt[4*i+3] += v.w;
            }
        }
        u32 s = 0;
        #pragma unroll
        for (int i = 0; i < 32; i++) s += cnt[i];
        u32 x = s;   // suffix-inclusive within wave (higher lane = higher bins)
        for (int off = 1; off < 64; off <<= 1) {
            u32 v = (u32)__shfl_down((int)x, off, 64);
            if (lane + off < 64) x += v;
        }
        if (lane == 0) sh.wtot[wv] = x;
        __syncthreads();
        u32 above = x - s;
        for (int w = wv + 1; w < 4; w++) above += sh.wtot[w];
        if (above < TOP_K && above + s >= TOP_K) {
            u32 cum = above;
            for (int i = 31; i >= 0; i--) {
                cum += cnt[i];
                if (cum >= TOP_K) {
                    st_sc(&state[1 * 32], (u32)(t * 32 + i));
                    st_sc(&state[0 * 32], TOP_K - (cum - cnt[i]));
                    break;
                }
            }
        }
    } else {
        // Warm this block's S3/S5 score slice into L1/L2 while block 0 scans.
        float acc = 0.0f;
        for (int a = gid; a < A; a += gstride) acc += scores[a];
        asm volatile("" :: "v"(acc));     // keep the loads alive
    }
    gbar(barr, 1, b, G, true);               // everyone needs d0cut

    // ---------- S3: pass-1 histogram (bits [18:3] of keys in cut d0 bin) ----------
    {
        u32 d0cut = state[1 * 32];           // first cached read of this line
        for (int a = gid; a < A; a += gstride) {
            u32 key = order_f32(scores[a]);  // L1/L2 hit (prefetched)
            if ((key >> (32 - D0_BITS)) == d0cut)
                atomicAdd(&hist1[(key >> 3) & 0xFFFFu], 1u);
        }
    }
    gbar(barr, 2, b, G, b == 0);             // only block 0 (S4) consumes hist1

    // ---------- S4: scan1 (block 0): d1 cut for k=k_rem ----------
    if (b == 0) {
        u32 k = state[0 * 32];
        const uint4* hp = (const uint4*)hist1;  // strip = bins [t*256, t*256+256)
        u32 chk[8]; u32 s = 0;
        #pragma unroll
        for (int c = 0; c < 8; c++) {
            u32 cs = 0;
            #pragma unroll
            for (int i = 0; i < 8; i++) {
                uint4 v = hp[t * 64 + c * 8 + i];
                cs += v.x + v.y + v.z + v.w;
            }
            chk[c] = cs; s += cs;
        }
        u32 x = s;
        for (int off = 1; off < 64; off <<= 1) {
            u32 v = (u32)__shfl_down((int)x, off, 64);
            if (lane + off < 64) x += v;
        }
        if (lane == 0) sh.wtot[wv] = x;
        __syncthreads();
        u32 above = x - s;
        for (int w = wv + 1; w < 4; w++) above += sh.wtot[w];
        if (above < k && above + s >= k) {
            u32 cum = above;
            bool done = false;
            for (int c = 7; c >= 0 && !done; c--) {
                if (cum + chk[c] >= k) {        // cut is inside chunk c
                    for (int i = 7; i >= 0 && !done; i--) {
                        uint4 v = hp[t * 64 + c * 8 + i];
                        u32 vv[4] = {v.x, v.y, v.z, v.w};
                        for (int q = 3; q >= 0 && !done; q--) {
                            cum += vv[q];
                            if (cum >= k) {
                                st_sc(&state[2 * 32], (u32)(t * 256 + c * 32 + i * 4 + q));
                                done = true;
                            }
                        }
                    }
                } else cum += chk[c];
            }
        }
    }
    gbar(barr, 3, b, G, true);               // everyone needs d1cut

    // ---------- S5: compact (pfx29 >= cut), two-sweep, ONE atomic per block ----------
    {
        u32 cut = (state[1 * 32] << 16) | state[2 * 32];
        int nr = (A + gstride - 1) / gstride;
        // sweep 1: count (scores are L1/L2-warm)
        u32 mycnt = 0;
        for (int r = 0; r < nr; r++) {
            int a = gid + r * gstride;
            mycnt += ((a < A) && ((order_f32(scores[a]) >> 3) >= cut)) ? 1u : 0u;
        }
        u32 wc = mycnt;
        wc += (u32)__shfl_xor((int)wc, 1, 64);
        wc += (u32)__shfl_xor((int)wc, 2, 64);
        wc += (u32)__shfl_xor((int)wc, 4, 64);
        wc += (u32)__shfl_xor((int)wc, 8, 64);
        wc += (u32)__shfl_xor((int)wc, 16, 64);
        wc += (u32)__shfl_xor((int)wc, 32, 64);
        if (lane == 0) sh.cmp.wcnt[wv] = wc;
        __syncthreads();
        if (t == 0) {
            u32 s = 0;
            #pragma unroll
            for (int w = 0; w < 4; w++) { sh.cmp.wbase[w] = s; s += sh.cmp.wcnt[w]; }
            sh.cmp.bbase = s ? atomicAdd(&state[5 * 32], s) : 0u;
        }
        __syncthreads();
        // sweep 2: ordered write (order within block irrelevant: keys unique,
        // rank-sort later is order-independent; n << CAND_CAP so no drops)
        u32 off = sh.cmp.bbase + sh.cmp.wbase[wv];
        for (int r = 0; r < nr; r++) {
            int a = gid + r * gstride;
            bool pass = (a < A) && ((order_f32(scores[a]) >> 3) >= cut);
            u64 mask = __ballot(pass ? 1 : 0);
            if (pass) {
                u32 pos = off + (u32)__popcll(mask & ((1ull << lane) - 1ull));
                if (pos < CAND_CAP) st_sc(&cand[pos], (u32)a);
            }
            off += (u32)__popcll(mask);
        }
    }
    gbar(barr, 4, b, G, b < CAND_CAP / 8);   // S6 participants wait

    // ---------- S6: exact parallel rank + decode ----------
    if (b < CAND_CAP / 8) {
        int n = (int)state[5 * 32]; if (n > CAND_CAP) n = CAND_CAP;   // first-touch
        u64 kj[8];                           // this thread's j-strip of keys
        #pragma unroll
        for (int q = 0; q < 8; q++) {
            int j = t * 8 + q;
            u64 kk = 0ull;                   // pads never outrank real keys
            if (j < n) {
                u32 a = cand[j];             // first-touch -> MALL, then cached
                kk = ((u64)order_f32(scores[a]) << 32) | (u64)(0xFFFFFFFFu - a);
            }
            kj[q] = kk;
        }
        for (int bb = b; bb < CAND_CAP / 8; bb += G) {
            if (t < 8) {
                int c = bb * 8 + t;
                u64 ck = 0ull;
                if (c < n) {
                    u32 a = cand[c];
                    ck = ((u64)order_f32(scores[a]) << 32) | (u64)(0xFFFFFFFFu - a);
                }
                sh.rank.ckeys[t] = ck;
            }
            __syncthreads();
            u64 ck[8];
            #pragma unroll
            for (int q = 0; q < 8; q++) ck[q] = sh.rank.ckeys[q];
            u32 cnt8[8] = {0,0,0,0,0,0,0,0};
            #pragma unroll
            for (int q = 0; q < 8; q++) {
                u64 kq = kj[q];
                #pragma unroll
                for (int q2 = 0; q2 < 8; q2++) cnt8[q2] += (kq > ck[q2]) ? 1u : 0u;
            }
            #pragma unroll
            for (int q2 = 0; q2 < 8; q2++) {
                u32 x = cnt8[q2];
                x += (u32)__shfl_xor((int)x, 1, 64);
                x += (u32)__shfl_xor((int)x, 2, 64);
                x += (u32)__shfl_xor((int)x, 4, 64);
                x += (u32)__shfl_xor((int)x, 8, 64);
                x += (u32)__shfl_xor((int)x, 16, 64);
                x += (u32)__shfl_xor((int)x, 32, 64);
                if (lane == 0) sh.rank.wpart[wv][q2] = x;
            }
            __syncthreads();
            if (t < 8) {
                int c = bb * 8 + t;
                if (c < n) {
                    u32 rank = sh.rank.wpart[0][t] + sh.rank.wpart[1][t]
                             + sh.rank.wpart[2][t] + sh.rank.wpart[3][t];
                    if (rank < TOP_K) {
                        u32 a = cand[c];
                        st_sc(&sidx[rank], a);
                        st_sc(&sscore[rank], scores[a]);
                        float4 an = *(const float4*)(anchors + (size_t)a * 4);
                        float4 rg = *(const float4*)(regs + (size_t)a * 4);
                        float aw = an.z - an.x, ah = an.w - an.y;
                        float acx = an.x + 0.5f * aw, acy = an.y + 0.5f * ah;
                        float pcx = acx + (rg.x * 0.1f) * aw;
                        float pcy = acy + (rg.y * 0.1f) * ah;
                        float pw = expf(rg.z * 0.2f) * aw;
                        float ph = expf(rg.w * 0.2f) * ah;
                        float W = (float)(*pW), H = (float)(*pH);
                        st_sc(&cbox[rank * 4 + 0], fminf(fmaxf(pcx - 0.5f * pw, 0.0f), W));
                        st_sc(&cbox[rank * 4 + 1], fminf(fmaxf(pcy - 0.5f * ph, 0.0f), H));
                        st_sc(&cbox[rank * 4 + 2], fminf(fmaxf(pcx + 0.5f * pw, 0.0f), W));
                        st_sc(&cbox[rank * 4 + 3], fminf(fmaxf(pcy + 0.5f * ph, 0.0f), H));
                    }
                }
            }
            __syncthreads();
        }
    }
    gbar(barr, 5, b, G, b * 4 < TOP_K);      // S7 participants wait

    // ---------- S7: IoU suppression bit-matrix (wave per row) ----------
    {
        const float4* B4 = (const float4*)cbox;   // first-touch -> MALL, then cached
        for (int i = b * 4 + wv; i < TOP_K; i += G * 4) {
            float4 bi = B4[i];
            float ai = fmaxf(bi.z - bi.x, 0.0f) * fmaxf(bi.w - bi.y, 0.0f);
            u64 any = 0ull;
            for (int w = 0; w < 16; w++) {
                int j = w * 64 + lane;
                bool sup = false;
                if (j < TOP_K && j > i) {
                    float4 bj = B4[j];
                    float aj = fmaxf(bj.z - bj.x, 0.0f) * fmaxf(bj.w - bj.y, 0.0f);
                    float xx1 = fmaxf(bi.x, bj.x), yy1 = fmaxf(bi.y, bj.y);
                    float xx2 = fminf(bi.z, bj.z), yy2 = fminf(bi.w, bj.w);
                    float inter = fmaxf(xx2 - xx1, 0.0f) * fmaxf(yy2 - yy1, 0.0f);
                    float iou = inter / (ai + aj - inter + 1e-8f);
                    sup = iou > IOU_THRESH;
                }
                u64 mask = __ballot(sup ? 1 : 0);
                if (lane == 0) { st_sc(&M[(size_t)i * 16 + w], mask); any |= mask; }
            }
            if (lane == 0) st_sc(&rflag[i], (any != 0ull) ? 1u : 0u);
        }
    }
    gbar(barr, 6, b, G, b == 0);             // only block 0 (S8) consumes

    // ---------- S8: greedy NMS over active rows + finalize (block 0) ----------
    if (b == 0) {
        {
            u32 nb = 0;
            int j0 = 4 * t;
            #pragma unroll
            for (int q = 0; q < 4; q++) {
                int j = j0 + q;
                if (j < TOP_K && sscore[j] > SCORE_THRESH) nb |= (1u << q);
            }
            sh.nms.nib[t] = nb;
        }
        u32 flags = 0; int cnt = 0;
        {
            int r0 = 4 * t;
            #pragma unroll
            for (int q = 0; q < 4; q++) {
                int r = r0 + q;
                if (r < TOP_K && rflag[r]) { flags |= (1u << q); cnt++; }
            }
        }
        int x = cnt;
        for (int off = 1; off < 64; off <<= 1) {
            int v = __shfl_up(x, off, 64);
            if (lane >= off) x += v;
        }
        if (lane == 63) sh.nms.wsum[wv] = (u32)x;
        __syncthreads();
        if (t < 16) {
            u64 w = 0;
            for (int m2 = 0; m2 < 16; m2++)
                w |= ((u64)sh.nms.nib[t * 16 + m2]) << (4 * m2);
            sh.nms.keepS[t] = w;
        }
        int base = 0;
        for (int w = 0; w < wv; w++) base += (int)sh.nms.wsum[w];
        int pos = base + x - cnt;
        {
            int r0 = 4 * t;
            #pragma unroll
            for (int q = 0; q < 4; q++)
                if (flags & (1u << q)) sh.nms.act[pos++] = r0 + q;
        }
        if (t == 0) {
            int na = 0;
            for (int w = 0; w < 4; w++) na += (int)sh.nms.wsum[w];
            sh.nms.nactS = na;
        }
        __syncthreads();
        int nact = sh.nms.nactS;
        int nchunks = (nact + NMS_CHUNK - 1) / NMS_CHUNK;

        // Double-buffered chunked greedy: waves 1-3 stage chunk ci+1 from MALL
        // while wave 0 runs the serial keep-chain on chunk ci, with the k+1
        // mask row prefetched into a register (chain = shfl+test+andnot).
        if (nchunks > 0) {
            int cn0 = (nact < NMS_CHUNK) ? nact : NMS_CHUNK;
            for (int i = t; i < cn0 * 16; i += 256) {
                int row = sh.nms.act[i >> 4];
                sh.nms.Ml[i] = M[(size_t)row * 16 + (i & 15)];
            }
        }
        __syncthreads();
        u64 kp = (wv == 0 && lane < 16) ? sh.nms.keepS[lane] : 0ull;
        for (int ci = 0; ci < nchunks; ci++) {
            int c0 = ci * NMS_CHUNK;
            int cn = (nact - c0 < NMS_CHUNK) ? (nact - c0) : NMS_CHUNK;
            int cur = (ci & 1) * (NMS_CHUNK * 16);
            if (ci + 1 < nchunks && t >= 64) {
                int c0n = c0 + NMS_CHUNK;
                int cnn = (nact - c0n < NMS_CHUNK) ? (nact - c0n) : NMS_CHUNK;
                int nxt = ((ci + 1) & 1) * (NMS_CHUNK * 16);
                for (int i = t - 64; i < cnn * 16; i += 192) {
                    int row = sh.nms.act[c0n + (i >> 4)];
                    sh.nms.Ml[nxt + i] = M[(size_t)row * 16 + (i & 15)];
                }
            }
            if (wv == 0) {
                u64 mreg = (lane < 16 && cn > 0) ? sh.nms.Ml[cur + lane] : 0ull;
                for (int k = 0; k < cn; k++) {
                    u64 mnx = (lane < 16 && k + 1 < cn)
                            ? sh.nms.Ml[cur + (k + 1) * 16 + lane] : 0ull;
                    int i = sh.nms.act[c0 + k];
                    u64 kw = __shfl(kp, i >> 6, 64);
                    if ((kw >> (i & 63)) & 1ull) kp &= ~mreg;
                    mreg = mnx;
                }
            }
            __syncthreads();
        }
        if (wv == 0 && lane < 16) sh.nms.keepS[lane] = kp;
        __syncthreads();

        if (t == 0) {
            int cnt2 = 0;
            for (int w = 0; w < 16 && cnt2 < MAX_DET; w++) {
                u64 kw = sh.nms.keepS[w];
                while (kw && cnt2 < MAX_DET) {
                    int bbit = __ffsll((unsigned long long)kw) - 1;
                    sh.nms.det[cnt2++] = w * 64 + bbit;
                    kw &= kw - 1;
                }
            }
            for (; cnt2 < MAX_DET; cnt2++) sh.nms.det[cnt2] = -1;
        }
        __syncthreads();
        if (t < MAX_DET) {
            int i = sh.nms.det[t];
            if (i >= 0) {
                u32 a = sidx[i];
                const float* p = cls + (size_t)a * C;
                float best = -1e30f; int bc = 0;
                if (C == 80) {
                    #pragma unroll
                    for (int c4 = 0; c4 < 20; c4++) {
                        float4 v = *(const float4*)(p + c4 * 4);
                        if (v.x > best) { best = v.x; bc = c4 * 4; }
                        if (v.y > best) { best = v.y; bc = c4 * 4 + 1; }
                        if (v.z > best) { best = v.z; bc = c4 * 4 + 2; }
                        if (v.w > best) { best = v.w; bc = c4 * 4 + 3; }
                    }
                } else {
                    best = p[0]; bc = 0;
                    for (int c = 1; c < C; c++) {
                        float v = p[c];
                        if (v > best) { best = v; bc = c; }
                    }
                }
                out[t] = best;
                out[MAX_DET + t] = (float)bc;
                out[2 * MAX_DET + t * 4 + 0] = cbox[i * 4 + 0];
                out[2 * MAX_DET + t * 4 + 1] = cbox[i * 4 + 1];
                out[2 * MAX_DET + t * 4 + 2] = cbox[i * 4 + 2];
                out[2 * MAX_DET + t * 4 + 3] = cbox[i * 4 + 3];
            } else {
                out[t] = 0.0f;
                out[MAX_DET + t] = -1.0f;
                out[2 * MAX_DET + t * 4 + 0] = 0.0f;
                out[2 * MAX_DET + t * 4 + 1] = 0.0f;
                out[2 * MAX_DET + t * 4 + 2] = 0.0f;
                out[2 * MAX_DET + t * 4 + 3] = 0.0f;
            }
        }
    }
}

extern "C" void kernel_launch(void* const* d_in, const int* in_sizes, int n_in,
                              void* d_out, int out_size, void* d_ws, size_t ws_size,
                              hipStream_t stream) {
    (void)n_in; (void)out_size; (void)ws_size;
    const float* cls     = (const float*)d_in[0];
    const float* regs    = (const float*)d_in[1];
    const float* anchors = (const float*)d_in[2];
    const int*   pH      = (const int*)d_in[3];
    const int*   pW      = (const int*)d_in[4];
    int A = in_sizes[1] / 4;
    int C = in_sizes[0] / A;

    // grid = 2 blocks/CU (<= 512 so flag rows of 512 u32 suffice):
    // co-residency guaranteed (37.6KB LDS -> 2 blocks/CU, launch_bounds(256,2)).
    static int nCU = 0;
    if (nCU <= 0) {
        int dev = 0;
        hipGetDevice(&dev);
        hipDeviceGetAttribute(&nCU, hipDeviceAttributeMultiprocessorCount, dev);
        if (nCU <= 0) nCU = 256;
    }
    int G = 2 * nCU;
    if (G > 512) G = 512;
    if (G < 8) G = 8;

    char* ws = (char*)d_ws;
    // Zero hist0 + hist1 + state + barrier flags in one memset; the fill
    // dispatch's completion makes the zeros coherence-point visible.
    hipMemsetAsync(ws, 0, MEMSET_LEN, stream);
    mega<<<dim3(G), dim3(256), 0, stream>>>(cls, regs, anchors, pH, pW, A, C,
                                            ws, (float*)d_out);
}

// Round 9
// 169.267 us; speedup vs baseline: 1.1096x; 1.1096x over previous
//
#include <hip/hip_runtime.h>
#include <stdint.h>

#define SCORE_THRESH 0.05f
#define IOU_THRESH 0.5f
#define TOP_K 1000
#define MAX_DET 100

#define D0_BITS 13
#define D0_BINS 8192           // 2^13
#define D1_BITS 12
#define D1_BINS 4096           // 12-bit refinement (R9: 16->12 so every block can
                               // redundantly scan hist1 cheaply; extras ~44 << cap)
#define NREP 4                 // replicated histograms (flush-contention relief)
#define CAND_CAP 2048
#define NMS_CHUNK 128          // rows per NMS staging chunk (dbuf: 2x128x16 u64 = 32KB)

typedef unsigned int u32;
typedef unsigned long long u64;

// ---- ws layout (bytes) ----
// [hist0][hist1][state][bar] is one contiguous host-memset region.
#define OFF_HIST0    0          // u32[NREP*8192] = 131072
#define OFF_HIST1    131072     // u32[NREP*4096] = 65536 -> 196608
#define OFF_STATE    196608     // u32 slots on own 128B lines: slot5=cand_cnt
#define OFF_BAR      197632     // 5 barriers x 4096B -> 218112
#define MEMSET_LEN   218112
#define OFF_CAND     218112     // u32[2048] -> 226304
#define OFF_RFLAG    226304     // u32[1000] -> 230304
#define OFF_SIDX     230304     // u32[1000] -> 234304
#define OFF_SSCORE   234304     // float[1000] -> 238304
#define OFF_CBOX     238304     // float[4000] -> 254304 (16B aligned)
#define OFF_M        254304     // u64[1000*16] = 128000 -> 382304 (8B aligned)
#define OFF_SCORES   382304     // float[A]

#define BAR_STRIDE_U32 1024     // 4KB per barrier: grp lines 0..7, root line 8

__device__ __forceinline__ u32 order_f32(float f) {
    u32 b = __float_as_uint(f);
    return (b & 0x80000000u) ? ~b : (b | 0x80000000u);
}

// MALL-direct (sc1) accessors: relaxed agent-scope atomics carry no fence, so
// NO buffer_wbl2 / buffer_inv is ever emitted. Stores write through to the
// coherence point without allocating L1/L2; loads bypass stale caches.
__device__ __forceinline__ void st_sc(u32* p, u32 v)   { __hip_atomic_store(p, v, __ATOMIC_RELAXED, __HIP_MEMORY_SCOPE_AGENT); }
__device__ __forceinline__ void st_sc(float* p, float v){ __hip_atomic_store(p, v, __ATOMIC_RELAXED, __HIP_MEMORY_SCOPE_AGENT); }
__device__ __forceinline__ void st_sc(u64* p, u64 v)   { __hip_atomic_store(p, v, __ATOMIC_RELAXED, __HIP_MEMORY_SCOPE_AGENT); }
__device__ __forceinline__ u32  ld_sc(u32* p)          { return __hip_atomic_load(p, __ATOMIC_RELAXED, __HIP_MEMORY_SCOPE_AGENT); }

// Device-wide barrier: counter-tree (R7 proven best at ~98us).
// R1: acquire-spin inv storm -> 620us. R2: release/acquire tag-walks -> 271us.
// R8: flag-array + full-sweep poll -> 124us (sweep-poll traffic REGRESSES;
// poll must touch ONE line). This version: 8-group fetch_add tree, root
// fetch_add, waiters poll root==8 with s_sleep(8).
// Correctness: explicit vmcnt(0) puts this block's sc1 stores at the
// coherence point before arrival; readers first-touch lines only after the
// producing barrier (layout discipline). gsz = arrivals per group (g = b&7).
__device__ __forceinline__ void gbar(u32* barr, int k, int b, u32 gsz, bool dowait) {
    __syncthreads();
    if (threadIdx.x == 0) {
        asm volatile("s_waitcnt vmcnt(0)" ::: "memory");
        u32* base = barr + (size_t)k * BAR_STRIDE_U32;
        int g = b & 7;
        if (__hip_atomic_fetch_add(base + g * 32, 1u, __ATOMIC_RELAXED,
                                   __HIP_MEMORY_SCOPE_AGENT) == gsz - 1u)
            __hip_atomic_fetch_add(base + 8 * 32, 1u, __ATOMIC_RELAXED,
                                   __HIP_MEMORY_SCOPE_AGENT);
        if (dowait) {
            while (ld_sc(base + 8 * 32) < 8u)
                __builtin_amdgcn_s_sleep(8);
        }
        asm volatile("" ::: "memory");
    }
    __syncthreads();
}

union ShMem {
    u32 hl[D0_BINS / 2];                               // 16 KB — S1 LDS histogram (u16-packed)
    u32 wtot[4];                                       // scan wave totals
    struct { u32 wcnt[4]; u32 wbase[4]; u32 bbase; } cmp;  // S5 compact
    struct { u64 ckeys[8]; u32 wpart[4][8]; } rank;    // S6
    struct {
        u64 Ml[2 * NMS_CHUNK * 16];                    // 32 KB double-buffered mask chunks
        u64 keepS[16];
        u32 nib[256];
        int act[TOP_K];
        u32 wsum[4];
        int nactS;
        int det[MAX_DET];
    } nms;                                             // ~37.6 KB total (proven footprint)
};

__global__ void __launch_bounds__(256, 2)
mega(const float* __restrict__ cls, const float* __restrict__ regs,
     const float* __restrict__ anchors, const int* __restrict__ pH,
     const int* __restrict__ pW, int A, int C,
     char* __restrict__ ws, float* __restrict__ out)
{
    __shared__ ShMem sh;
    __shared__ u32 shcut[3];     // [0]=d0cut [1]=k_rem [2]=d1cut (block-local copy)
    u32*   hist0  = (u32*)(ws + OFF_HIST0);
    u32*   hist1  = (u32*)(ws + OFF_HIST1);
    u32*   state  = (u32*)(ws + OFF_STATE);   // slot 5 (cand_cnt) at state[5*32]
    u32*   barr   = (u32*)(ws + OFF_BAR);
    u32*   cand   = (u32*)(ws + OFF_CAND);
    u32*   rflag  = (u32*)(ws + OFF_RFLAG);
    u32*   sidx   = (u32*)(ws + OFF_SIDX);
    float* sscore = (float*)(ws + OFF_SSCORE);
    float* cbox   = (float*)(ws + OFF_CBOX);
    u64*   M      = (u64*)(ws + OFF_M);
    float* scores = (float*)(ws + OFF_SCORES);

    const int t = threadIdx.x;
    const int b = blockIdx.x;
    const int G = gridDim.x;
    const int gid = b * 256 + t;
    const int gstride = G * 256;
    const int lane = t & 63, wv = t >> 6;
    const u32 gsz = (u32)(G >> 3);

    // ---------- S1: coalesced class-max + thresholded score + pass-0 hist ----------
    // hist0/hist1/state/bar were zeroed by the host memset (prior dispatch).
    if (C == 80) {
        for (int i = t; i < D0_BINS / 2; i += 256) sh.hl[i] = 0;
        __syncthreads();
        int sub = t & 3;           // which 20-float quarter of the 80 classes
        int la  = t >> 2;          // local anchor 0..63
        int nstrips = (A + 63) >> 6;
        int per = (nstrips + G - 1) / G;
        for (int s = 0; s < per; s++) {
            int a = (b * per + s) * 64 + la;
            float m = -1e30f;
            if (a < A) {
                const float* p = cls + (size_t)a * 80 + sub * 4;
                #pragma unroll
                for (int k2 = 0; k2 < 5; k2++) {
                    float4 v = *(const float4*)(p + k2 * 16);
                    m = fmaxf(m, fmaxf(fmaxf(v.x, v.y), fmaxf(v.z, v.w)));
                }
            }
            m = fmaxf(m, __shfl_xor(m, 1, 64));
            m = fmaxf(m, __shfl_xor(m, 2, 64));
            if (sub == 0 && a < A) {
                float s0 = (m > SCORE_THRESH) ? m : -1.0f;
                st_sc(&scores[a], s0);                  // sc1: visible at MALL
                u32 d = order_f32(s0) >> (32 - D0_BITS);
                atomicAdd(&sh.hl[d >> 1], (d & 1) ? 0x10000u : 1u);
            }
        }
        __syncthreads();
        u32* rep = hist0 + (size_t)(b & (NREP - 1)) * D0_BINS;
        for (int i = t; i < D0_BINS / 2; i += 256) {
            u32 v = sh.hl[i];
            if (v & 0xFFFFu) atomicAdd(&rep[2 * i],     v & 0xFFFFu);   // memory-side RMW
            if (v >> 16)     atomicAdd(&rep[2 * i + 1], v >> 16);
        }
    } else {
        u32* rep = hist0 + (size_t)(b & (NREP - 1)) * D0_BINS;
        for (int a = gid; a < A; a += gstride) {
            const float* p = cls + (size_t)a * C;
            float m = -1e30f;
            for (int c = 0; c < C; c++) m = fmaxf(m, p[c]);
            float s0 = (m > SCORE_THRESH) ? m : -1.0f;
            st_sc(&scores[a], s0);
            atomicAdd(&rep[order_f32(s0) >> (32 - D0_BITS)], 1u);
        }
    }
    gbar(barr, 0, b, gsz, true);             // hist0 complete; everyone scans it

    // ---------- S2: scan0, REDUNDANT in every block (R9) ----------
    // All blocks read the same NREP*32KB of hist0 (MALL-resident, read-only,
    // deterministic -> identical d0cut/k_rem everywhere). Replaces block-0
    // serial scan + broadcast barrier: one barrier and one serial stage gone.
    {
        u32 cnt[32];
        #pragma unroll
        for (int i = 0; i < 32; i++) cnt[i] = 0;
        const uint4* hp = (const uint4*)hist0;
        #pragma unroll
        for (int r = 0; r < NREP; r++) {
            #pragma unroll
            for (int i = 0; i < 8; i++) {
                uint4 v = hp[r * (D0_BINS / 4) + t * 8 + i];
                cnt[4*i]   += v.x; cnt[4*i+1] += v.y;
                cnt[4*i+2] += v.z; cnt[4*i+3] += v.w;
            }
        }
        u32 s = 0;
        #pragma unroll
        for (int i = 0; i < 32; i++) s += cnt[i];
        u32 x = s;   // suffix-inclusive within wave (higher lane = higher bins)
        for (int off = 1; off < 64; off <<= 1) {
            u32 v = (u32)__shfl_down((int)x, off, 64);
            if (lane + off < 64) x += v;
        }
        if (lane == 0) sh.wtot[wv] = x;
        __syncthreads();
        u32 above = x - s;
        for (int w = wv + 1; w < 4; w++) above += sh.wtot[w];
        if (above < TOP_K && above + s >= TOP_K) {
            u32 cum = above;
            for (int i = 31; i >= 0; i--) {
                cum += cnt[i];
                if (cum >= TOP_K) {
                    shcut[0] = (u32)(t * 32 + i);
                    shcut[1] = TOP_K - (cum - cnt[i]);
                    break;
                }
            }
        }
        __syncthreads();
    }
    const u32 d0cut = shcut[0];
    const u32 krem  = shcut[1];

    // ---------- S3: pass-1 histogram (12-bit, key bits [18:7], cut d0 bin) ----------
    {
        u32* rep1 = hist1 + (size_t)(b & (NREP - 1)) * D1_BINS;
        for (int a = gid; a < A; a += gstride) {
            u32 key = order_f32(scores[a]);
            if ((key >> (32 - D0_BITS)) == d0cut)
                atomicAdd(&rep1[(key >> 7) & (D1_BINS - 1)], 1u);
        }
    }
    gbar(barr, 1, b, gsz, true);             // hist1 complete; everyone scans it

    // ---------- S4: scan1, REDUNDANT in every block (16 bins/thread) ----------
    {
        u32 cnt[16];
        #pragma unroll
        for (int i = 0; i < 16; i++) cnt[i] = 0;
        const uint4* hp = (const uint4*)hist1;
        #pragma unroll
        for (int r = 0; r < NREP; r++) {
            #pragma unroll
            for (int i = 0; i < 4; i++) {
                uint4 v = hp[r * (D1_BINS / 4) + t * 4 + i];
                cnt[4*i]   += v.x; cnt[4*i+1] += v.y;
                cnt[4*i+2] += v.z; cnt[4*i+3] += v.w;
            }
        }
        u32 s = 0;
        #pragma unroll
        for (int i = 0; i < 16; i++) s += cnt[i];
        u32 x = s;
        for (int off = 1; off < 64; off <<= 1) {
            u32 v = (u32)__shfl_down((int)x, off, 64);
            if (lane + off < 64) x += v;
        }
        if (lane == 0) sh.wtot[wv] = x;
        __syncthreads();
        u32 above = x - s;
        for (int w = wv + 1; w < 4; w++) above += sh.wtot[w];
        if (above < krem && above + s >= krem) {
            u32 cum = above;
            for (int i = 15; i >= 0; i--) {
                cum += cnt[i];
                if (cum >= krem) { shcut[2] = (u32)(t * 16 + i); break; }
            }
        }
        __syncthreads();
    }
    const u32 cut25 = (d0cut << D1_BITS) | shcut[2];

    // ---------- S5: compact (prefix25 >= cut25), two-sweep, ONE atomic/block ----------
    // No barrier between S4 and S5: every block derived cut25 locally.
    {
        int nr = (A + gstride - 1) / gstride;
        u32 mycnt = 0;
        for (int r = 0; r < nr; r++) {
            int a = gid + r * gstride;
            mycnt += ((a < A) && ((order_f32(scores[a]) >> 7) >= cut25)) ? 1u : 0u;
        }
        u32 wc = mycnt;
        wc += (u32)__shfl_xor((int)wc, 1, 64);
        wc += (u32)__shfl_xor((int)wc, 2, 64);
        wc += (u32)__shfl_xor((int)wc, 4, 64);
        wc += (u32)__shfl_xor((int)wc, 8, 64);
        wc += (u32)__shfl_xor((int)wc, 16, 64);
        wc += (u32)__shfl_xor((int)wc, 32, 64);
        if (lane == 0) sh.cmp.wcnt[wv] = wc;
        __syncthreads();
        if (t == 0) {
            u32 s = 0;
            #pragma unroll
            for (int w = 0; w < 4; w++) { sh.cmp.wbase[w] = s; s += sh.cmp.wcnt[w]; }
            sh.cmp.bbase = s ? atomicAdd(&state[5 * 32], s) : 0u;
        }
        __syncthreads();
        u32 off = sh.cmp.bbase + sh.cmp.wbase[wv];
        for (int r = 0; r < nr; r++) {
            int a = gid + r * gstride;
            bool pass = (a < A) && ((order_f32(scores[a]) >> 7) >= cut25);
            u64 mask = __ballot(pass ? 1 : 0);
            if (pass) {
                u32 pos = off + (u32)__popcll(mask & ((1ull << lane) - 1ull));
                if (pos < CAND_CAP) st_sc(&cand[pos], (u32)a);
            }
            off += (u32)__popcll(mask);
        }
    }
    gbar(barr, 2, b, gsz, b < CAND_CAP / 8); // S6 participants wait

    // ---------- S6: exact parallel rank + decode ----------
    if (b < CAND_CAP / 8) {
        int n = (int)state[5 * 32]; if (n > CAND_CAP) n = CAND_CAP;   // first-touch
        u64 kj[8];                           // this thread's j-strip of keys
        #pragma unroll
        for (int q = 0; q < 8; q++) {
            int j = t * 8 + q;
            u64 kk = 0ull;                   // pads never outrank real keys
            if (j < n) {
                u32 a = cand[j];             // first-touch -> MALL, then cached
                kk = ((u64)order_f32(scores[a]) << 32) | (u64)(0xFFFFFFFFu - a);
            }
            kj[q] = kk;
        }
        for (int bb = b; bb < CAND_CAP / 8; bb += G) {
            if (t < 8) {
                int c = bb * 8 + t;
                u64 ck = 0ull;
                if (c < n) {
                    u32 a = cand[c];
                    ck = ((u64)order_f32(scores[a]) << 32) | (u64)(0xFFFFFFFFu - a);
                }
                sh.rank.ckeys[t] = ck;
            }
            __syncthreads();
            u64 ck[8];
            #pragma unroll
            for (int q = 0; q < 8; q++) ck[q] = sh.rank.ckeys[q];
            u32 cnt8[8] = {0,0,0,0,0,0,0,0};
            #pragma unroll
            for (int q = 0; q < 8; q++) {
                u64 kq = kj[q];
                #pragma unroll
                for (int q2 = 0; q2 < 8; q2++) cnt8[q2] += (kq > ck[q2]) ? 1u : 0u;
            }
            #pragma unroll
            for (int q2 = 0; q2 < 8; q2++) {
                u32 x = cnt8[q2];
                x += (u32)__shfl_xor((int)x, 1, 64);
                x += (u32)__shfl_xor((int)x, 2, 64);
                x += (u32)__shfl_xor((int)x, 4, 64);
                x += (u32)__shfl_xor((int)x, 8, 64);
                x += (u32)__shfl_xor((int)x, 16, 64);
                x += (u32)__shfl_xor((int)x, 32, 64);
                if (lane == 0) sh.rank.wpart[wv][q2] = x;
            }
            __syncthreads();
            if (t < 8) {
                int c = bb * 8 + t;
                if (c < n) {
                    u32 rank = sh.rank.wpart[0][t] + sh.rank.wpart[1][t]
                             + sh.rank.wpart[2][t] + sh.rank.wpart[3][t];
                    if (rank < TOP_K) {
                        u32 a = cand[c];
                        st_sc(&sidx[rank], a);
                        st_sc(&sscore[rank], scores[a]);
                        float4 an = *(const float4*)(anchors + (size_t)a * 4);
                        float4 rg = *(const float4*)(regs + (size_t)a * 4);
                        float aw = an.z - an.x, ah = an.w - an.y;
                        float acx = an.x + 0.5f * aw, acy = an.y + 0.5f * ah;
                        float pcx = acx + (rg.x * 0.1f) * aw;
                        float pcy = acy + (rg.y * 0.1f) * ah;
                        float pw = expf(rg.z * 0.2f) * aw;
                        float ph = expf(rg.w * 0.2f) * ah;
                        float W = (float)(*pW), H = (float)(*pH);
                        st_sc(&cbox[rank * 4 + 0], fminf(fmaxf(pcx - 0.5f * pw, 0.0f), W));
                        st_sc(&cbox[rank * 4 + 1], fminf(fmaxf(pcy - 0.5f * ph, 0.0f), H));
                        st_sc(&cbox[rank * 4 + 2], fminf(fmaxf(pcx + 0.5f * pw, 0.0f), W));
                        st_sc(&cbox[rank * 4 + 3], fminf(fmaxf(pcy + 0.5f * ph, 0.0f), H));
                    }
                }
            }
            __syncthreads();
        }
    }
    gbar(barr, 3, b, gsz, b * 4 < TOP_K);    // S7 participants wait

    // ---------- S7: IoU suppression bit-matrix (wave per row) ----------
    {
        const float4* B4 = (const float4*)cbox;   // first-touch -> MALL, then cached
        for (int i = b * 4 + wv; i < TOP_K; i += G * 4) {
            float4 bi = B4[i];
            float ai = fmaxf(bi.z - bi.x, 0.0f) * fmaxf(bi.w - bi.y, 0.0f);
            u64 any = 0ull;
            for (int w = 0; w < 16; w++) {
                int j = w * 64 + lane;
                bool sup = false;
                if (j < TOP_K && j > i) {
                    float4 bj = B4[j];
                    float aj = fmaxf(bj.z - bj.x, 0.0f) * fmaxf(bj.w - bj.y, 0.0f);
                    float xx1 = fmaxf(bi.x, bj.x), yy1 = fmaxf(bi.y, bj.y);
                    float xx2 = fminf(bi.z, bj.z), yy2 = fminf(bi.w, bj.w);
                    float inter = fmaxf(xx2 - xx1, 0.0f) * fmaxf(yy2 - yy1, 0.0f);
                    float iou = inter / (ai + aj - inter + 1e-8f);
                    sup = iou > IOU_THRESH;
                }
                u64 mask = __ballot(sup ? 1 : 0);
                if (lane == 0) { st_sc(&M[(size_t)i * 16 + w], mask); any |= mask; }
            }
            if (lane == 0) st_sc(&rflag[i], (any != 0ull) ? 1u : 0u);
        }
    }
    gbar(barr, 4, b, gsz, b == 0);           // only block 0 (S8) consumes

    // ---------- S8: greedy NMS over active rows + finalize (block 0) ----------
    if (b == 0) {
        {
            u32 nb = 0;
            int j0 = 4 * t;
            #pragma unroll
            for (int q = 0; q < 4; q++) {
                int j = j0 + q;
                if (j < TOP_K && sscore[j] > SCORE_THRESH) nb |= (1u << q);
            }
            sh.nms.nib[t] = nb;
        }
        u32 flags = 0; int cnt = 0;
        {
            int r0 = 4 * t;
            #pragma unroll
            for (int q = 0; q < 4; q++) {
                int r = r0 + q;
                if (r < TOP_K && rflag[r]) { flags |= (1u << q); cnt++; }
            }
        }
        int x = cnt;
        for (int off = 1; off < 64; off <<= 1) {
            int v = __shfl_up(x, off, 64);
            if (lane >= off) x += v;
        }
        if (lane == 63) sh.nms.wsum[wv] = (u32)x;
        __syncthreads();
        if (t < 16) {
            u64 w = 0;
            for (int m2 = 0; m2 < 16; m2++)
                w |= ((u64)sh.nms.nib[t * 16 + m2]) << (4 * m2);
            sh.nms.keepS[t] = w;
        }
        int base = 0;
        for (int w = 0; w < wv; w++) base += (int)sh.nms.wsum[w];
        int pos = base + x - cnt;
        {
            int r0 = 4 * t;
            #pragma unroll
            for (int q = 0; q < 4; q++)
                if (flags & (1u << q)) sh.nms.act[pos++] = r0 + q;
        }
        if (t == 0) {
            int na = 0;
            for (int w = 0; w < 4; w++) na += (int)sh.nms.wsum[w];
            sh.nms.nactS = na;
        }
        __syncthreads();
        int nact = sh.nms.nactS;
        int nchunks = (nact + NMS_CHUNK - 1) / NMS_CHUNK;

        // Double-buffered chunked greedy with register-prefetched mask rows.
        if (nchunks > 0) {
            int cn0 = (nact < NMS_CHUNK) ? nact : NMS_CHUNK;
            for (int i = t; i < cn0 * 16; i += 256) {
                int row = sh.nms.act[i >> 4];
                sh.nms.Ml[i] = M[(size_t)row * 16 + (i & 15)];
            }
        }
        __syncthreads();
        u64 kp = (wv == 0 && lane < 16) ? sh.nms.keepS[lane] : 0ull;
        for (int ci = 0; ci < nchunks; ci++) {
            int c0 = ci * NMS_CHUNK;
            int cn = (nact - c0 < NMS_CHUNK) ? (nact - c0) : NMS_CHUNK;
            int cur = (ci & 1) * (NMS_CHUNK * 16);
            if (ci + 1 < nchunks && t >= 64) {
                int c0n = c0 + NMS_CHUNK;
                int cnn = (nact - c0n < NMS_CHUNK) ? (nact - c0n) : NMS_CHUNK;
                int nxt = ((ci + 1) & 1) * (NMS_CHUNK * 16);
                for (int i = t - 64; i < cnn * 16; i += 192) {
                    int row = sh.nms.act[c0n + (i >> 4)];
                    sh.nms.Ml[nxt + i] = M[(size_t)row * 16 + (i & 15)];
                }
            }
            if (wv == 0) {
                u64 mreg = (lane < 16 && cn > 0) ? sh.nms.Ml[cur + lane] : 0ull;
                for (int k = 0; k < cn; k++) {
                    u64 mnx = (lane < 16 && k + 1 < cn)
                            ? sh.nms.Ml[cur + (k + 1) * 16 + lane] : 0ull;
                    int i = sh.nms.act[c0 + k];
                    u64 kw = __shfl(kp, i >> 6, 64);
                    if ((kw >> (i & 63)) & 1ull) kp &= ~mreg;
                    mreg = mnx;
                }
            }
            __syncthreads();
        }
        if (wv == 0 && lane < 16) sh.nms.keepS[lane] = kp;
        __syncthreads();

        if (t == 0) {
            int cnt2 = 0;
            for (int w = 0; w < 16 && cnt2 < MAX_DET; w++) {
                u64 kw = sh.nms.keepS[w];
                while (kw && cnt2 < MAX_DET) {
                    int bbit = __ffsll((unsigned long long)kw) - 1;
                    sh.nms.det[cnt2++] = w * 64 + bbit;
                    kw &= kw - 1;
                }
            }
            for (; cnt2 < MAX_DET; cnt2++) sh.nms.det[cnt2] = -1;
        }
        __syncthreads();
        if (t < MAX_DET) {
            int i = sh.nms.det[t];
            if (i >= 0) {
                u32 a = sidx[i];
                const float* p = cls + (size_t)a * C;
                float best = -1e30f; int bc = 0;
                if (C == 80) {
                    #pragma unroll
                    for (int c4 = 0; c4 < 20; c4++) {
                        float4 v = *(const float4*)(p + c4 * 4);
                        if (v.x > best) { best = v.x; bc = c4 * 4; }
                        if (v.y > best) { best = v.y; bc = c4 * 4 + 1; }
                        if (v.z > best) { best = v.z; bc = c4 * 4 + 2; }
                        if (v.w > best) { best = v.w; bc = c4 * 4 + 3; }
                    }
                } else {
                    best = p[0]; bc = 0;
                    for (int c = 1; c < C; c++) {
                        float v = p[c];
                        if (v > best) { best = v; bc = c; }
                    }
                }
                out[t] = best;
                out[MAX_DET + t] = (float)bc;
                out[2 * MAX_DET + t * 4 + 0] = cbox[i * 4 + 0];
                out[2 * MAX_DET + t * 4 + 1] = cbox[i * 4 + 1];
                out[2 * MAX_DET + t * 4 + 2] = cbox[i * 4 + 2];
                out[2 * MAX_DET + t * 4 + 3] = cbox[i * 4 + 3];
            } else {
                out[t] = 0.0f;
                out[MAX_DET + t] = -1.0f;
                out[2 * MAX_DET + t * 4 + 0] = 0.0f;
                out[2 * MAX_DET + t * 4 + 1] = 0.0f;
                out[2 * MAX_DET + t * 4 + 2] = 0.0f;
                out[2 * MAX_DET + t * 4 + 3] = 0.0f;
            }
        }
    }
}

extern "C" void kernel_launch(void* const* d_in, const int* in_sizes, int n_in,
                              void* d_out, int out_size, void* d_ws, size_t ws_size,
                              hipStream_t stream) {
    (void)n_in; (void)out_size; (void)ws_size;
    const float* cls     = (const float*)d_in[0];
    const float* regs    = (const float*)d_in[1];
    const float* anchors = (const float*)d_in[2];
    const int*   pH      = (const int*)d_in[3];
    const int*   pW      = (const int*)d_in[4];
    int A = in_sizes[1] / 4;
    int C = in_sizes[0] / A;

    // grid = 2 blocks/CU, multiple of 8 (barrier tree groups):
    // co-residency guaranteed (37.6KB LDS -> 2 blocks/CU, launch_bounds(256,2)).
    static int nCU = 0;
    if (nCU <= 0) {
        int dev = 0;
        hipGetDevice(&dev);
        hipDeviceGetAttribute(&nCU, hipDeviceAttributeMultiprocessorCount, dev);
        if (nCU <= 0) nCU = 256;
    }
    int G = (2 * nCU) & ~7;
    if (G < 8) G = 8;

    char* ws = (char*)d_ws;
    // Zero hist0 + hist1 + state + barrier tree in one memset; the fill
    // dispatch's completion makes the zeros coherence-point visible.
    hipMemsetAsync(ws, 0, MEMSET_LEN, stream);
    mega<<<dim3(G), dim3(256), 0, stream>>>(cls, regs, anchors, pH, pW, A, C,
                                            ws, (float*)d_out);
}

// Round 10
// 153.276 us; speedup vs baseline: 1.2254x; 1.1043x over previous
//
#include <hip/hip_runtime.h>
#include <stdint.h>

#define SCORE_THRESH 0.05f
#define IOU_THRESH 0.5f
#define TOP_K 1000
#define MAX_DET 100

#define UBINS 4096             // 12-bit nonuniform bins on u=1-s (exp+5 mantissa)
#define NREP 4                 // replicated histograms (flush-contention relief)
#define CAND_CAP 2048
#define NMS_CHUNK 128          // rows per NMS staging chunk (dbuf: 2x128x16 u64 = 32KB)

typedef unsigned int u32;
typedef unsigned long long u64;

// ---- ws layout (bytes) ----
// [hist][state][bar] is one contiguous host-memset region.
#define OFF_HIST     0          // u32[NREP*4096] = 65536
#define OFF_STATE    65536      // 1024 -> 66560 (slot5 = cand_cnt at [5*32])
#define OFF_BAR      66560      // 4 barriers x 4096B -> 82944
#define MEMSET_LEN   82944
#define OFF_CAND     82944      // u32[2048] -> 91136
#define OFF_RFLAG    91136      // u32[1000] -> 95136
#define OFF_SIDX     95136      // u32[1000] -> 99136
#define OFF_SSCORE   99136      // float[1000] -> 103136
#define OFF_CBOX     103136     // float[4000] -> 119136 (16B aligned)
#define OFF_M        119136     // u64[1000*16] = 128000 -> 247136 (8B aligned)
#define OFF_SCORES   247136     // float[A]

#define BAR_STRIDE_U32 1024     // per barrier: flags[0..511], go word at [512]

__device__ __forceinline__ u32 order_f32(float f) {
    u32 b = __float_as_uint(f);
    return (b & 0x80000000u) ? ~b : (b | 0x80000000u);
}

// Distribution-matched 12-bit bin, ASCENDING in u=1-s (i.e. descending score).
// u = 1-s is exact for s in [0.5,1] (Sterbenz) and monotone elsewhere, so
// bin(s) is monotone non-increasing in s -> {bin <= cut} is a clean superset
// of any score-prefix set. Exponent bits give log-scale tail resolution:
// at the top-1000 cut (u ~ 6e-5) a bin holds ~31 anchors -> ONE histogram
// pass suffices (replaces R9's two-level 13+12-bit radix; -1 barrier,
// -1 score sweep). Sentinel s0=-1 -> u=2.0 -> bin 4096, clamped to 4095
// (region [1.96875,2) is unpopulated, so the clamp collides with nothing).
__device__ __forceinline__ u32 ubin(float s0) {
    float u = 1.0f - s0;
    u32 bin = __float_as_uint(u) >> 18;      // sign(0)+exp(8)+mantissa(5)
    return bin > (UBINS - 1) ? (UBINS - 1) : bin;
}

// MALL-direct (sc1) accessors: relaxed agent-scope atomics carry no fence ->
// no buffer_wbl2/buffer_inv ever. Stores write through to the coherence
// point; loads bypass stale caches.
__device__ __forceinline__ void st_sc(u32* p, u32 v)   { __hip_atomic_store(p, v, __ATOMIC_RELAXED, __HIP_MEMORY_SCOPE_AGENT); }
__device__ __forceinline__ void st_sc(float* p, float v){ __hip_atomic_store(p, v, __ATOMIC_RELAXED, __HIP_MEMORY_SCOPE_AGENT); }
__device__ __forceinline__ void st_sc(u64* p, u64 v)   { __hip_atomic_store(p, v, __ATOMIC_RELAXED, __HIP_MEMORY_SCOPE_AGENT); }
__device__ __forceinline__ u32  ld_sc(u32* p)          { return __hip_atomic_load(p, __ATOMIC_RELAXED, __HIP_MEMORY_SCOPE_AGENT); }

// Device-wide barrier v5: parallel flag arrival + SINGLE sweeper + go poll.
// Ledger: R1 acquire-spin inv storm 620us; R2 release/acquire tag-walks
// 271us; R3/R7 counter-tree 98us (two serialized RMW levels per arrival);
// R8 flag-array with ALL-blocks sweep-poll 124us (sweep cost x512).
// v5 keeps R8's parallel arrival (1 sc1 store/block, no RMW) but only
// block 0 sweeps the flags (2 loads/thread/iter); everyone else polls the
// one-line go word (R7's proven pattern). Block 0 waits at every barrier
// by construction, so it is always an eligible sweeper.
// Correctness: __syncthreads before arrival drains all waves' vmcnt (HIP
// barrier semantics) -> this block's sc1 data stores are at the coherence
// point before its flag store. Readers first-touch data lines only after
// the producing barrier (layout discipline). Flags monotone 0->1,
// host-zeroed; non-waiting blocks may race ahead safely.
__device__ __forceinline__ void gbar(u32* barr, int k, int b, int G, bool dowait) {
    __syncthreads();
    u32* base = barr + (size_t)k * BAR_STRIDE_U32;
    if (threadIdx.x == 0) {
        asm volatile("s_waitcnt vmcnt(0)" ::: "memory");
        st_sc(&base[b], 1u);
    }
    if (!dowait) return;
    if (b == 0) {
        for (;;) {
            int my = 1;
            for (int i = (int)threadIdx.x; i < G; i += 256) my &= (int)ld_sc(&base[i]);
            if (__syncthreads_and(my)) break;
        }
        if (threadIdx.x == 0) st_sc(&base[512], 1u);
    } else {
        if (threadIdx.x == 0) {
            while (ld_sc(&base[512]) == 0u) __builtin_amdgcn_s_sleep(8);
        }
    }
    __syncthreads();
    asm volatile("" ::: "memory");
}

union ShMem {
    u32 hl[UBINS / 2];                                 // 8 KB — S1 LDS histogram (u16-packed)
    u32 wtot[4];                                       // scan wave totals
    struct { u32 wcnt[4]; u32 wbase[4]; u32 bbase; } cmp;  // compact
    struct { u64 ckeys[8]; u32 wpart[4][8]; } rank;    // rank
    struct {
        u64 Ml[2 * NMS_CHUNK * 16];                    // 32 KB double-buffered mask chunks
        u64 keepS[16];
        u32 nib[256];
        int act[TOP_K];
        u32 wsum[4];
        int nactS;
        int det[MAX_DET];
    } nms;                                             // ~37.6 KB total (proven footprint)
};

__global__ void __launch_bounds__(256, 2)
mega(const float* __restrict__ cls, const float* __restrict__ regs,
     const float* __restrict__ anchors, const int* __restrict__ pH,
     const int* __restrict__ pW, int A, int C,
     char* __restrict__ ws, float* __restrict__ out)
{
    __shared__ ShMem sh;
    __shared__ u32 shcut;        // block-local cut bin
    u32*   hist   = (u32*)(ws + OFF_HIST);
    u32*   state  = (u32*)(ws + OFF_STATE);   // slot 5 (cand_cnt) at state[5*32]
    u32*   barr   = (u32*)(ws + OFF_BAR);
    u32*   cand   = (u32*)(ws + OFF_CAND);
    u32*   rflag  = (u32*)(ws + OFF_RFLAG);
    u32*   sidx   = (u32*)(ws + OFF_SIDX);
    float* sscore = (float*)(ws + OFF_SSCORE);
    float* cbox   = (float*)(ws + OFF_CBOX);
    u64*   M      = (u64*)(ws + OFF_M);
    float* scores = (float*)(ws + OFF_SCORES);

    const int t = threadIdx.x;
    const int b = blockIdx.x;
    const int G = gridDim.x;
    const int gid = b * 256 + t;
    const int gstride = G * 256;
    const int lane = t & 63, wv = t >> 6;

    // ---------- S1: coalesced class-max + thresholded score + u-bin hist ----------
    // hist/state/bar were zeroed by the host memset (prior dispatch).
    if (C == 80) {
        for (int i = t; i < UBINS / 2; i += 256) sh.hl[i] = 0;
        __syncthreads();
        int sub = t & 3;           // which 20-float quarter of the 80 classes
        int la  = t >> 2;          // local anchor 0..63
        int nstrips = (A + 63) >> 6;
        int per = (nstrips + G - 1) / G;
        for (int s = 0; s < per; s++) {
            int a = (b * per + s) * 64 + la;
            float m = -1e30f;
            if (a < A) {
                const float* p = cls + (size_t)a * 80 + sub * 4;
                #pragma unroll
                for (int k2 = 0; k2 < 5; k2++) {
                    float4 v = *(const float4*)(p + k2 * 16);
                    m = fmaxf(m, fmaxf(fmaxf(v.x, v.y), fmaxf(v.z, v.w)));
                }
            }
            m = fmaxf(m, __shfl_xor(m, 1, 64));
            m = fmaxf(m, __shfl_xor(m, 2, 64));
            if (sub == 0 && a < A) {
                float s0 = (m > SCORE_THRESH) ? m : -1.0f;
                st_sc(&scores[a], s0);                  // sc1: visible at MALL
                u32 d = ubin(s0);
                atomicAdd(&sh.hl[d >> 1], (d & 1) ? 0x10000u : 1u);
            }
        }
        __syncthreads();
        u32* rep = hist + (size_t)(b & (NREP - 1)) * UBINS;
        for (int i = t; i < UBINS / 2; i += 256) {
            u32 v = sh.hl[i];
            if (v & 0xFFFFu) atomicAdd(&rep[2 * i],     v & 0xFFFFu);   // memory-side RMW
            if (v >> 16)     atomicAdd(&rep[2 * i + 1], v >> 16);
        }
    } else {
        u32* rep = hist + (size_t)(b & (NREP - 1)) * UBINS;
        for (int a = gid; a < A; a += gstride) {
            const float* p = cls + (size_t)a * C;
            float m = -1e30f;
            for (int c = 0; c < C; c++) m = fmaxf(m, p[c]);
            float s0 = (m > SCORE_THRESH) ? m : -1.0f;
            st_sc(&scores[a], s0);
            atomicAdd(&rep[ubin(s0)], 1u);
        }
    }
    gbar(barr, 0, b, G, true);               // hist complete; everyone scans it

    // ---------- S2: single scan, REDUNDANT in every block ----------
    // All blocks read the same NREP*16KB (MALL-resident, read-only,
    // deterministic -> identical cut everywhere). 16 bins/thread, ascending
    // prefix; cut = first bin where cum >= TOP_K.
    {
        if (t == 0) shcut = UBINS - 1;       // default: include all (A < TOP_K case)
        u32 cnt[16];
        #pragma unroll
        for (int i = 0; i < 16; i++) cnt[i] = 0;
        const uint4* hp = (const uint4*)hist;
        #pragma unroll
        for (int r = 0; r < NREP; r++) {
            #pragma unroll
            for (int i = 0; i < 4; i++) {
                uint4 v = hp[r * (UBINS / 4) + t * 4 + i];
                cnt[4*i]   += v.x; cnt[4*i+1] += v.y;
                cnt[4*i+2] += v.z; cnt[4*i+3] += v.w;
            }
        }
        u32 s = 0;
        #pragma unroll
        for (int i = 0; i < 16; i++) s += cnt[i];
        u32 x = s;   // inclusive prefix within wave (ascending lanes)
        for (int off = 1; off < 64; off <<= 1) {
            u32 v = (u32)__shfl_up((int)x, off, 64);
            if (lane >= off) x += v;
        }
        if (lane == 63) sh.wtot[wv] = x;
        __syncthreads();
        u32 below = x - s;
        for (int w = 0; w < wv; w++) below += sh.wtot[w];
        if (below < TOP_K && below + s >= TOP_K) {
            u32 cum = below;
            for (int i = 0; i < 16; i++) {
                cum += cnt[i];
                if (cum >= TOP_K) { shcut = (u32)(t * 16 + i); break; }
            }
        }
        __syncthreads();
    }
    const u32 cutbin = shcut;

    // ---------- S3: compact (ubin <= cutbin), two-sweep, ONE atomic/block ----------
    // No barrier needed after the scan: every block derived cutbin locally.
    {
        int nr = (A + gstride - 1) / gstride;
        u32 mycnt = 0;
        for (int r = 0; r < nr; r++) {
            int a = gid + r * gstride;
            mycnt += ((a < A) && (ubin(scores[a]) <= cutbin)) ? 1u : 0u;
        }
        u32 wc = mycnt;
        wc += (u32)__shfl_xor((int)wc, 1, 64);
        wc += (u32)__shfl_xor((int)wc, 2, 64);
        wc += (u32)__shfl_xor((int)wc, 4, 64);
        wc += (u32)__shfl_xor((int)wc, 8, 64);
        wc += (u32)__shfl_xor((int)wc, 16, 64);
        wc += (u32)__shfl_xor((int)wc, 32, 64);
        if (lane == 0) sh.cmp.wcnt[wv] = wc;
        __syncthreads();
        if (t == 0) {
            u32 s = 0;
            #pragma unroll
            for (int w = 0; w < 4; w++) { sh.cmp.wbase[w] = s; s += sh.cmp.wcnt[w]; }
            sh.cmp.bbase = s ? atomicAdd(&state[5 * 32], s) : 0u;
        }
        __syncthreads();
        u32 off = sh.cmp.bbase + sh.cmp.wbase[wv];
        for (int r = 0; r < nr; r++) {
            int a = gid + r * gstride;
            bool pass = (a < A) && (ubin(scores[a]) <= cutbin);
            u64 mask = __ballot(pass ? 1 : 0);
            if (pass) {
                u32 pos = off + (u32)__popcll(mask & ((1ull << lane) - 1ull));
                if (pos < CAND_CAP) st_sc(&cand[pos], (u32)a);
            }
            off += (u32)__popcll(mask);
        }
    }
    gbar(barr, 1, b, G, b < CAND_CAP / 8);   // rank participants wait

    // ---------- S4: exact parallel rank + decode ----------
    if (b < CAND_CAP / 8) {
        int n = (int)state[5 * 32]; if (n > CAND_CAP) n = CAND_CAP;   // first-touch
        u64 kj[8];                           // this thread's j-strip of keys
        #pragma unroll
        for (int q = 0; q < 8; q++) {
            int j = t * 8 + q;
            u64 kk = 0ull;                   // pads never outrank real keys
            if (j < n) {
                u32 a = cand[j];             // first-touch -> MALL, then cached
                kk = ((u64)order_f32(scores[a]) << 32) | (u64)(0xFFFFFFFFu - a);
            }
            kj[q] = kk;
        }
        for (int bb = b; bb < CAND_CAP / 8; bb += G) {
            if (t < 8) {
                int c = bb * 8 + t;
                u64 ck = 0ull;
                if (c < n) {
                    u32 a = cand[c];
                    ck = ((u64)order_f32(scores[a]) << 32) | (u64)(0xFFFFFFFFu - a);
                }
                sh.rank.ckeys[t] = ck;
            }
            __syncthreads();
            u64 ck[8];
            #pragma unroll
            for (int q = 0; q < 8; q++) ck[q] = sh.rank.ckeys[q];
            u32 cnt8[8] = {0,0,0,0,0,0,0,0};
            #pragma unroll
            for (int q = 0; q < 8; q++) {
                u64 kq = kj[q];
                #pragma unroll
                for (int q2 = 0; q2 < 8; q2++) cnt8[q2] += (kq > ck[q2]) ? 1u : 0u;
            }
            #pragma unroll
            for (int q2 = 0; q2 < 8; q2++) {
                u32 x = cnt8[q2];
                x += (u32)__shfl_xor((int)x, 1, 64);
                x += (u32)__shfl_xor((int)x, 2, 64);
                x += (u32)__shfl_xor((int)x, 4, 64);
                x += (u32)__shfl_xor((int)x, 8, 64);
                x += (u32)__shfl_xor((int)x, 16, 64);
                x += (u32)__shfl_xor((int)x, 32, 64);
                if (lane == 0) sh.rank.wpart[wv][q2] = x;
            }
            __syncthreads();
            if (t < 8) {
                int c = bb * 8 + t;
                if (c < n) {
                    u32 rank = sh.rank.wpart[0][t] + sh.rank.wpart[1][t]
                             + sh.rank.wpart[2][t] + sh.rank.wpart[3][t];
                    if (rank < TOP_K) {
                        u32 a = cand[c];
                        st_sc(&sidx[rank], a);
                        st_sc(&sscore[rank], scores[a]);
                        float4 an = *(const float4*)(anchors + (size_t)a * 4);
                        float4 rg = *(const float4*)(regs + (size_t)a * 4);
                        float aw = an.z - an.x, ah = an.w - an.y;
                        float acx = an.x + 0.5f * aw, acy = an.y + 0.5f * ah;
                        float pcx = acx + (rg.x * 0.1f) * aw;
                        float pcy = acy + (rg.y * 0.1f) * ah;
                        float pw = expf(rg.z * 0.2f) * aw;
                        float ph = expf(rg.w * 0.2f) * ah;
                        float W = (float)(*pW), H = (float)(*pH);
                        st_sc(&cbox[rank * 4 + 0], fminf(fmaxf(pcx - 0.5f * pw, 0.0f), W));
                        st_sc(&cbox[rank * 4 + 1], fminf(fmaxf(pcy - 0.5f * ph, 0.0f), H));
                        st_sc(&cbox[rank * 4 + 2], fminf(fmaxf(pcx + 0.5f * pw, 0.0f), W));
                        st_sc(&cbox[rank * 4 + 3], fminf(fmaxf(pcy + 0.5f * ph, 0.0f), H));
                    }
                }
            }
            __syncthreads();
        }
    }
    gbar(barr, 2, b, G, b * 4 < TOP_K);      // IoU participants wait

    // ---------- S5: IoU suppression bit-matrix (wave per row) ----------
    {
        const float4* B4 = (const float4*)cbox;   // first-touch -> MALL, then cached
        for (int i = b * 4 + wv; i < TOP_K; i += G * 4) {
            float4 bi = B4[i];
            float ai = fmaxf(bi.z - bi.x, 0.0f) * fmaxf(bi.w - bi.y, 0.0f);
            u64 any = 0ull;
            for (int w = 0; w < 16; w++) {
                int j = w * 64 + lane;
                bool sup = false;
                if (j < TOP_K && j > i) {
                    float4 bj = B4[j];
                    float aj = fmaxf(bj.z - bj.x, 0.0f) * fmaxf(bj.w - bj.y, 0.0f);
                    float xx1 = fmaxf(bi.x, bj.x), yy1 = fmaxf(bi.y, bj.y);
                    float xx2 = fminf(bi.z, bj.z), yy2 = fminf(bi.w, bj.w);
                    float inter = fmaxf(xx2 - xx1, 0.0f) * fmaxf(yy2 - yy1, 0.0f);
                    float iou = inter / (ai + aj - inter + 1e-8f);
                    sup = iou > IOU_THRESH;
                }
                u64 mask = __ballot(sup ? 1 : 0);
                if (lane == 0) { st_sc(&M[(size_t)i * 16 + w], mask); any |= mask; }
            }
            if (lane == 0) st_sc(&rflag[i], (any != 0ull) ? 1u : 0u);
        }
    }
    gbar(barr, 3, b, G, b == 0);             // only block 0 (S6) consumes

    // ---------- S6: greedy NMS over active rows + finalize (block 0) ----------
    if (b == 0) {
        {
            u32 nb = 0;
            int j0 = 4 * t;
            #pragma unroll
            for (int q = 0; q < 4; q++) {
                int j = j0 + q;
                if (j < TOP_K && sscore[j] > SCORE_THRESH) nb |= (1u << q);
            }
            sh.nms.nib[t] = nb;
        }
        u32 flags = 0; int cnt = 0;
        {
            int r0 = 4 * t;
            #pragma unroll
            for (int q = 0; q < 4; q++) {
                int r = r0 + q;
                if (r < TOP_K && rflag[r]) { flags |= (1u << q); cnt++; }
            }
        }
        int x = cnt;
        for (int off = 1; off < 64; off <<= 1) {
            int v = __shfl_up(x, off, 64);
            if (lane >= off) x += v;
        }
        if (lane == 63) sh.nms.wsum[wv] = (u32)x;
        __syncthreads();
        if (t < 16) {
            u64 w = 0;
            for (int m2 = 0; m2 < 16; m2++)
                w |= ((u64)sh.nms.nib[t * 16 + m2]) << (4 * m2);
            sh.nms.keepS[t] = w;
        }
        int base = 0;
        for (int w = 0; w < wv; w++) base += (int)sh.nms.wsum[w];
        int pos = base + x - cnt;
        {
            int r0 = 4 * t;
            #pragma unroll
            for (int q = 0; q < 4; q++)
                if (flags & (1u << q)) sh.nms.act[pos++] = r0 + q;
        }
        if (t == 0) {
            int na = 0;
            for (int w = 0; w < 4; w++) na += (int)sh.nms.wsum[w];
            sh.nms.nactS = na;
        }
        __syncthreads();
        int nact = sh.nms.nactS;
        int nchunks = (nact + NMS_CHUNK - 1) / NMS_CHUNK;

        // Double-buffered chunked greedy with register-prefetched mask rows.
        if (nchunks > 0) {
            int cn0 = (nact < NMS_CHUNK) ? nact : NMS_CHUNK;
            for (int i = t; i < cn0 * 16; i += 256) {
                int row = sh.nms.act[i >> 4];
                sh.nms.Ml[i] = M[(size_t)row * 16 + (i & 15)];
            }
        }
        __syncthreads();
        u64 kp = (wv == 0 && lane < 16) ? sh.nms.keepS[lane] : 0ull;
        for (int ci = 0; ci < nchunks; ci++) {
            int c0 = ci * NMS_CHUNK;
            int cn = (nact - c0 < NMS_CHUNK) ? (nact - c0) : NMS_CHUNK;
            int cur = (ci & 1) * (NMS_CHUNK * 16);
            if (ci + 1 < nchunks && t >= 64) {
                int c0n = c0 + NMS_CHUNK;
                int cnn = (nact - c0n < NMS_CHUNK) ? (nact - c0n) : NMS_CHUNK;
                int nxt = ((ci + 1) & 1) * (NMS_CHUNK * 16);
                for (int i = t - 64; i < cnn * 16; i += 192) {
                    int row = sh.nms.act[c0n + (i >> 4)];
                    sh.nms.Ml[nxt + i] = M[(size_t)row * 16 + (i & 15)];
                }
            }
            if (wv == 0) {
                u64 mreg = (lane < 16 && cn > 0) ? sh.nms.Ml[cur + lane] : 0ull;
                for (int k = 0; k < cn; k++) {
                    u64 mnx = (lane < 16 && k + 1 < cn)
                            ? sh.nms.Ml[cur + (k + 1) * 16 + lane] : 0ull;
                    int i = sh.nms.act[c0 + k];
                    u64 kw = __shfl(kp, i >> 6, 64);
                    if ((kw >> (i & 63)) & 1ull) kp &= ~mreg;
                    mreg = mnx;
                }
            }
            __syncthreads();
        }
        if (wv == 0 && lane < 16) sh.nms.keepS[lane] = kp;
        __syncthreads();

        if (t == 0) {
            int cnt2 = 0;
            for (int w = 0; w < 16 && cnt2 < MAX_DET; w++) {
                u64 kw = sh.nms.keepS[w];
                while (kw && cnt2 < MAX_DET) {
                    int bbit = __ffsll((unsigned long long)kw) - 1;
                    sh.nms.det[cnt2++] = w * 64 + bbit;
                    kw &= kw - 1;
                }
            }
            for (; cnt2 < MAX_DET; cnt2++) sh.nms.det[cnt2] = -1;
        }
        __syncthreads();
        if (t < MAX_DET) {
            int i = sh.nms.det[t];
            if (i >= 0) {
                u32 a = sidx[i];
                const float* p = cls + (size_t)a * C;
                float best = -1e30f; int bc = 0;
                if (C == 80) {
                    #pragma unroll
                    for (int c4 = 0; c4 < 20; c4++) {
                        float4 v = *(const float4*)(p + c4 * 4);
                        if (v.x > best) { best = v.x; bc = c4 * 4; }
                        if (v.y > best) { best = v.y; bc = c4 * 4 + 1; }
                        if (v.z > best) { best = v.z; bc = c4 * 4 + 2; }
                        if (v.w > best) { best = v.w; bc = c4 * 4 + 3; }
                    }
                } else {
                    best = p[0]; bc = 0;
                    for (int c = 1; c < C; c++) {
                        float v = p[c];
                        if (v > best) { best = v; bc = c; }
                    }
                }
                out[t] = best;
                out[MAX_DET + t] = (float)bc;
                out[2 * MAX_DET + t * 4 + 0] = cbox[i * 4 + 0];
                out[2 * MAX_DET + t * 4 + 1] = cbox[i * 4 + 1];
                out[2 * MAX_DET + t * 4 + 2] = cbox[i * 4 + 2];
                out[2 * MAX_DET + t * 4 + 3] = cbox[i * 4 + 3];
            } else {
                out[t] = 0.0f;
                out[MAX_DET + t] = -1.0f;
                out[2 * MAX_DET + t * 4 + 0] = 0.0f;
                out[2 * MAX_DET + t * 4 + 1] = 0.0f;
                out[2 * MAX_DET + t * 4 + 2] = 0.0f;
                out[2 * MAX_DET + t * 4 + 3] = 0.0f;
            }
        }
    }
}

extern "C" void kernel_launch(void* const* d_in, const int* in_sizes, int n_in,
                              void* d_out, int out_size, void* d_ws, size_t ws_size,
                              hipStream_t stream) {
    (void)n_in; (void)out_size; (void)ws_size;
    const float* cls     = (const float*)d_in[0];
    const float* regs    = (const float*)d_in[1];
    const float* anchors = (const float*)d_in[2];
    const int*   pH      = (const int*)d_in[3];
    const int*   pW      = (const int*)d_in[4];
    int A = in_sizes[1] / 4;
    int C = in_sizes[0] / A;

    // grid = 2 blocks/CU, capped at 512 (flag-row capacity):
    // co-residency guaranteed (37.6KB LDS -> 2 blocks/CU, launch_bounds(256,2)).
    static int nCU = 0;
    if (nCU <= 0) {
        int dev = 0;
        hipGetDevice(&dev);
        hipDeviceGetAttribute(&nCU, hipDeviceAttributeMultiprocessorCount, dev);
        if (nCU <= 0) nCU = 256;
    }
    int G = 2 * nCU;
    if (G > 512) G = 512;
    if (G < 8) G = 8;

    char* ws = (char*)d_ws;
    // Zero hist + state + barrier flags in one memset; the fill dispatch's
    // completion makes the zeros coherence-point visible.
    hipMemsetAsync(ws, 0, MEMSET_LEN, stream);
    mega<<<dim3(G), dim3(256), 0, stream>>>(cls, regs, anchors, pH, pW, A, C,
                                            ws, (float*)d_out);
}

// Round 11
// 150.154 us; speedup vs baseline: 1.2509x; 1.0208x over previous
//
#include <hip/hip_runtime.h>
#include <stdint.h>

#define SCORE_THRESH 0.05f
#define IOU_THRESH 0.5f
#define TOP_K 1000
#define MAX_DET 100

#define UBINS 4096             // 12-bit nonuniform bins on u=1-s (exp+5 mantissa)
#define NREP 4                 // replicated histograms (flush-contention relief)
#define CAND_CAP 2048
#define NMS_CHUNK 128          // rows per NMS staging chunk (dbuf: 2x128x16 u64 = 32KB)

typedef unsigned int u32;
typedef unsigned long long u64;

// ---- ws layout (bytes) ----
// [hist][state][bar] is one contiguous host-memset region.
#define OFF_HIST     0          // u32[NREP*4096] = 65536
#define OFF_STATE    65536      // 1024 -> 66560 (slot5 = cand_cnt at [5*32])
#define OFF_BAR      66560      // 4 barriers x 4096B -> 82944
#define MEMSET_LEN   82944
#define OFF_CAND     82944      // u64[2048] = 16384 -> 99328 (R11: full keys, no rank gather)
#define OFF_RFLAG    99328      // u32[1000] -> 103328
#define OFF_SIDX     103328     // u32[1000] -> 107328
#define OFF_SSCORE   107328     // float[1000] -> 111328
#define OFF_CBOX     111328     // float[4000] -> 127328 (16B aligned)
#define OFF_M        127328     // u64[1000*16] = 128000 -> 255328 (8B aligned)
#define OFF_SCORES   255328     // float[A]

#define BAR_STRIDE_U32 1024     // per barrier: flags[0..511], go word at [512]

__device__ __forceinline__ u32 order_f32(float f) {
    u32 b = __float_as_uint(f);
    return (b & 0x80000000u) ? ~b : (b | 0x80000000u);
}

// Distribution-matched 12-bit bin, ASCENDING in u=1-s (descending score).
// Exact for s in [0.5,1] (Sterbenz), monotone everywhere; exponent bits give
// log-scale tail resolution so ONE histogram pass resolves the top-1000 cut
// (cut bin holds ~31 anchors). Sentinel s0=-1 -> u=2.0 -> clamped 4095.
__device__ __forceinline__ u32 ubin(float s0) {
    float u = 1.0f - s0;
    u32 bin = __float_as_uint(u) >> 18;      // sign(0)+exp(8)+mantissa(5)
    return bin > (UBINS - 1) ? (UBINS - 1) : bin;
}

// MALL-direct (sc1) accessors: relaxed agent-scope atomics carry no fence ->
// no buffer_wbl2/buffer_inv ever. Stores write through to the coherence
// point; loads bypass stale caches.
__device__ __forceinline__ void st_sc(u32* p, u32 v)   { __hip_atomic_store(p, v, __ATOMIC_RELAXED, __HIP_MEMORY_SCOPE_AGENT); }
__device__ __forceinline__ void st_sc(float* p, float v){ __hip_atomic_store(p, v, __ATOMIC_RELAXED, __HIP_MEMORY_SCOPE_AGENT); }
__device__ __forceinline__ void st_sc(u64* p, u64 v)   { __hip_atomic_store(p, v, __ATOMIC_RELAXED, __HIP_MEMORY_SCOPE_AGENT); }
__device__ __forceinline__ u32  ld_sc(u32* p)          { return __hip_atomic_load(p, __ATOMIC_RELAXED, __HIP_MEMORY_SCOPE_AGENT); }

// Device-wide barrier v5 (R10-proven): parallel flag arrival (1 sc1 store
// per block, zero RMWs) + SINGLE sweeper (block 0, 2 loads/thread) + one-line
// go-word poll for everyone else. Ledger: R1 inv-storm 620us; R2 tag-walks
// 271us; R3/R7 counter-tree 98us; R8 all-blocks-sweep 124us; v5 -> 73us.
// Correctness: __syncthreads + vmcnt(0) put this block's sc1 data stores at
// the coherence point before its flag store; readers first-touch data lines
// only after the producing barrier (layout discipline). Flags monotone 0->1,
// host-zeroed; non-waiting blocks race ahead safely.
__device__ __forceinline__ void gbar(u32* barr, int k, int b, int G, bool dowait) {
    __syncthreads();
    u32* base = barr + (size_t)k * BAR_STRIDE_U32;
    if (threadIdx.x == 0) {
        asm volatile("s_waitcnt vmcnt(0)" ::: "memory");
        st_sc(&base[b], 1u);
    }
    if (!dowait) return;
    if (b == 0) {
        for (;;) {
            int my = 1;
            for (int i = (int)threadIdx.x; i < G; i += 256) my &= (int)ld_sc(&base[i]);
            if (__syncthreads_and(my)) break;
        }
        if (threadIdx.x == 0) st_sc(&base[512], 1u);
    } else {
        if (threadIdx.x == 0) {
            while (ld_sc(&base[512]) == 0u) __builtin_amdgcn_s_sleep(8);
        }
    }
    __syncthreads();
    asm volatile("" ::: "memory");
}

union ShMem {
    u32 hl[UBINS / 2];                                 // 8 KB — S1 LDS histogram (u16-packed)
    u32 wtot[4];                                       // scan wave totals
    struct { u32 wcnt[4]; u32 wbase[4]; u32 bbase; } cmp;  // compact
    struct { u64 ckeys[8]; u32 wpart[4][8]; } rank;    // rank
    struct {
        u64 Ml[2 * NMS_CHUNK * 16];                    // 32 KB double-buffered mask chunks
        u64 keepS[16];
        u32 nib[256];
        int act[TOP_K];
        u32 wsum[4];
        int nactS;
        int det[MAX_DET];
    } nms;                                             // ~37.6 KB total (proven footprint)
};

__global__ void __launch_bounds__(256, 2)
mega(const float* __restrict__ cls, const float* __restrict__ regs,
     const float* __restrict__ anchors, const int* __restrict__ pH,
     const int* __restrict__ pW, int A, int C,
     char* __restrict__ ws, float* __restrict__ out)
{
    __shared__ ShMem sh;
    __shared__ u32 shcut;        // block-local cut bin
    u32*   hist   = (u32*)(ws + OFF_HIST);
    u32*   state  = (u32*)(ws + OFF_STATE);   // slot 5 (cand_cnt) at state[5*32]
    u32*   barr   = (u32*)(ws + OFF_BAR);
    u64*   cand   = (u64*)(ws + OFF_CAND);    // full sort keys (score||~a)
    u32*   rflag  = (u32*)(ws + OFF_RFLAG);
    u32*   sidx   = (u32*)(ws + OFF_SIDX);
    float* sscore = (float*)(ws + OFF_SSCORE);
    float* cbox   = (float*)(ws + OFF_CBOX);
    u64*   M      = (u64*)(ws + OFF_M);
    float* scores = (float*)(ws + OFF_SCORES);

    const int t = threadIdx.x;
    const int b = blockIdx.x;
    const int G = gridDim.x;
    const int gid = b * 256 + t;
    const int gstride = G * 256;
    const int lane = t & 63, wv = t >> 6;

    // ---------- S1: coalesced class-max + thresholded score + u-bin hist ----------
    // hist/state/bar were zeroed by the host memset (prior dispatch).
    if (C == 80) {
        for (int i = t; i < UBINS / 2; i += 256) sh.hl[i] = 0;
        __syncthreads();
        int sub = t & 3;           // which 20-float quarter of the 80 classes
        int la  = t >> 2;          // local anchor 0..63
        int nstrips = (A + 63) >> 6;
        int per = (nstrips + G - 1) / G;
        for (int s = 0; s < per; s++) {
            int a = (b * per + s) * 64 + la;
            float m = -1e30f;
            if (a < A) {
                const float* p = cls + (size_t)a * 80 + sub * 4;
                #pragma unroll
                for (int k2 = 0; k2 < 5; k2++) {
                    float4 v = *(const float4*)(p + k2 * 16);
                    m = fmaxf(m, fmaxf(fmaxf(v.x, v.y), fmaxf(v.z, v.w)));
                }
            }
            m = fmaxf(m, __shfl_xor(m, 1, 64));
            m = fmaxf(m, __shfl_xor(m, 2, 64));
            if (sub == 0 && a < A) {
                float s0 = (m > SCORE_THRESH) ? m : -1.0f;
                st_sc(&scores[a], s0);                  // sc1: visible at MALL
                u32 d = ubin(s0);
                atomicAdd(&sh.hl[d >> 1], (d & 1) ? 0x10000u : 1u);
            }
        }
        __syncthreads();
        u32* rep = hist + (size_t)(b & (NREP - 1)) * UBINS;
        for (int i = t; i < UBINS / 2; i += 256) {
            u32 v = sh.hl[i];
            if (v & 0xFFFFu) atomicAdd(&rep[2 * i],     v & 0xFFFFu);   // memory-side RMW
            if (v >> 16)     atomicAdd(&rep[2 * i + 1], v >> 16);
        }
    } else {
        u32* rep = hist + (size_t)(b & (NREP - 1)) * UBINS;
        for (int a = gid; a < A; a += gstride) {
            const float* p = cls + (size_t)a * C;
            float m = -1e30f;
            for (int c = 0; c < C; c++) m = fmaxf(m, p[c]);
            float s0 = (m > SCORE_THRESH) ? m : -1.0f;
            st_sc(&scores[a], s0);
            atomicAdd(&rep[ubin(s0)], 1u);
        }
    }
    gbar(barr, 0, b, G, true);               // hist complete; everyone scans it

    // ---------- S2: single scan, REDUNDANT in every block ----------
    {
        if (t == 0) shcut = UBINS - 1;       // default: include all (A < TOP_K case)
        u32 cnt[16];
        #pragma unroll
        for (int i = 0; i < 16; i++) cnt[i] = 0;
        const uint4* hp = (const uint4*)hist;
        #pragma unroll
        for (int r = 0; r < NREP; r++) {
            #pragma unroll
            for (int i = 0; i < 4; i++) {
                uint4 v = hp[r * (UBINS / 4) + t * 4 + i];
                cnt[4*i]   += v.x; cnt[4*i+1] += v.y;
                cnt[4*i+2] += v.z; cnt[4*i+3] += v.w;
            }
        }
        u32 s = 0;
        #pragma unroll
        for (int i = 0; i < 16; i++) s += cnt[i];
        u32 x = s;   // inclusive prefix within wave (ascending lanes)
        for (int off = 1; off < 64; off <<= 1) {
            u32 v = (u32)__shfl_up((int)x, off, 64);
            if (lane >= off) x += v;
        }
        if (lane == 63) sh.wtot[wv] = x;
        __syncthreads();
        u32 below = x - s;
        for (int w = 0; w < wv; w++) below += sh.wtot[w];
        if (below < TOP_K && below + s >= TOP_K) {
            u32 cum = below;
            for (int i = 0; i < 16; i++) {
                cum += cnt[i];
                if (cum >= TOP_K) { shcut = (u32)(t * 16 + i); break; }
            }
        }
        __syncthreads();
    }
    const u32 cutbin = shcut;

    // ---------- S3: compact (ubin <= cutbin) -> 64-bit KEYS, one atomic/block ----------
    // R11: cand stores (order(score)||~a). Rank then needs ONE contiguous 16KB
    // load instead of ~1030 scattered score-gathers per participating block.
    {
        int nr = (A + gstride - 1) / gstride;
        u32 mycnt = 0;
        for (int r = 0; r < nr; r++) {
            int a = gid + r * gstride;
            mycnt += ((a < A) && (ubin(scores[a]) <= cutbin)) ? 1u : 0u;
        }
        u32 wc = mycnt;
        wc += (u32)__shfl_xor((int)wc, 1, 64);
        wc += (u32)__shfl_xor((int)wc, 2, 64);
        wc += (u32)__shfl_xor((int)wc, 4, 64);
        wc += (u32)__shfl_xor((int)wc, 8, 64);
        wc += (u32)__shfl_xor((int)wc, 16, 64);
        wc += (u32)__shfl_xor((int)wc, 32, 64);
        if (lane == 0) sh.cmp.wcnt[wv] = wc;
        __syncthreads();
        if (t == 0) {
            u32 s = 0;
            #pragma unroll
            for (int w = 0; w < 4; w++) { sh.cmp.wbase[w] = s; s += sh.cmp.wcnt[w]; }
            sh.cmp.bbase = s ? atomicAdd(&state[5 * 32], s) : 0u;
        }
        __syncthreads();
        u32 off = sh.cmp.bbase + sh.cmp.wbase[wv];
        for (int r = 0; r < nr; r++) {
            int a = gid + r * gstride;
            float s0 = (a < A) ? scores[a] : 0.0f;
            bool pass = (a < A) && (ubin(s0) <= cutbin);
            u64 mask = __ballot(pass ? 1 : 0);
            if (pass) {
                u32 pos = off + (u32)__popcll(mask & ((1ull << lane) - 1ull));
                if (pos < CAND_CAP) {
                    u64 key = ((u64)order_f32(s0) << 32) | (u64)(0xFFFFFFFFu - (u32)a);
                    st_sc(&cand[pos], key);
                }
            }
            off += (u32)__popcll(mask);
        }
    }
    gbar(barr, 1, b, G, b < CAND_CAP / 8);   // rank participants wait

    // ---------- S4: exact parallel rank + decode ----------
    if (b < CAND_CAP / 8) {
        int n = (int)state[5 * 32]; if (n > CAND_CAP) n = CAND_CAP;   // first-touch
        u64 kj[8];                           // this thread's j-strip of keys
        #pragma unroll
        for (int q = 0; q < 8; q++) {
            int j = t * 8 + q;
            kj[q] = (j < n) ? cand[j] : 0ull;    // contiguous; pads sort last
        }
        for (int bb = b; bb < CAND_CAP / 8; bb += G) {
            if (t < 8) {
                int c = bb * 8 + t;
                sh.rank.ckeys[t] = (c < n) ? cand[c] : 0ull;
            }
            __syncthreads();
            u64 ck[8];
            #pragma unroll
            for (int q = 0; q < 8; q++) ck[q] = sh.rank.ckeys[q];
            u32 cnt8[8] = {0,0,0,0,0,0,0,0};
            #pragma unroll
            for (int q = 0; q < 8; q++) {
                u64 kq = kj[q];
                #pragma unroll
                for (int q2 = 0; q2 < 8; q2++) cnt8[q2] += (kq > ck[q2]) ? 1u : 0u;
            }
            #pragma unroll
            for (int q2 = 0; q2 < 8; q2++) {
                u32 x = cnt8[q2];
                x += (u32)__shfl_xor((int)x, 1, 64);
                x += (u32)__shfl_xor((int)x, 2, 64);
                x += (u32)__shfl_xor((int)x, 4, 64);
                x += (u32)__shfl_xor((int)x, 8, 64);
                x += (u32)__shfl_xor((int)x, 16, 64);
                x += (u32)__shfl_xor((int)x, 32, 64);
                if (lane == 0) sh.rank.wpart[wv][q2] = x;
            }
            __syncthreads();
            if (t < 8) {
                int c = bb * 8 + t;
                if (c < n) {
                    u32 rank = sh.rank.wpart[0][t] + sh.rank.wpart[1][t]
                             + sh.rank.wpart[2][t] + sh.rank.wpart[3][t];
                    if (rank < TOP_K) {
                        u64 kk = ck[t];
                        u32 a = 0xFFFFFFFFu - (u32)(kk & 0xFFFFFFFFull);
                        u32 hi = (u32)(kk >> 32);
                        u32 bits = (hi & 0x80000000u) ? (hi & 0x7FFFFFFFu) : ~hi;
                        st_sc(&sidx[rank], a);
                        st_sc(&sscore[rank], __uint_as_float(bits));
                        float4 an = *(const float4*)(anchors + (size_t)a * 4);
                        float4 rg = *(const float4*)(regs + (size_t)a * 4);
                        float aw = an.z - an.x, ah = an.w - an.y;
                        float acx = an.x + 0.5f * aw, acy = an.y + 0.5f * ah;
                        float pcx = acx + (rg.x * 0.1f) * aw;
                        float pcy = acy + (rg.y * 0.1f) * ah;
                        float pw = expf(rg.z * 0.2f) * aw;
                        float ph = expf(rg.w * 0.2f) * ah;
                        float W = (float)(*pW), H = (float)(*pH);
                        st_sc(&cbox[rank * 4 + 0], fminf(fmaxf(pcx - 0.5f * pw, 0.0f), W));
                        st_sc(&cbox[rank * 4 + 1], fminf(fmaxf(pcy - 0.5f * ph, 0.0f), H));
                        st_sc(&cbox[rank * 4 + 2], fminf(fmaxf(pcx + 0.5f * pw, 0.0f), W));
                        st_sc(&cbox[rank * 4 + 3], fminf(fmaxf(pcy + 0.5f * ph, 0.0f), H));
                    }
                }
            }
            __syncthreads();
        }
    }
    gbar(barr, 2, b, G, b == 0 || (b - 1) * 4 < TOP_K);   // IoU + block 0 wait

    // ---------- S5: IoU bit-matrix on blocks 1..250 ∥ keep-init on block 0 ----------
    if (b >= 1) {
        const float4* B4 = (const float4*)cbox;   // first-touch -> MALL, then cached
        for (int i = (b - 1) * 4 + wv; i < TOP_K; i += (G - 1) * 4) {
            float4 bi = B4[i];
            float ai = fmaxf(bi.z - bi.x, 0.0f) * fmaxf(bi.w - bi.y, 0.0f);
            u64 any = 0ull;
            int w0 = i >> 6;                      // words < w0: all j < i -> zero
            if (lane == 0)
                for (int w = 0; w < w0; w++) st_sc(&M[(size_t)i * 16 + w], 0ull);
            for (int w = w0; w < 16; w++) {
                int j = w * 64 + lane;
                bool sup = false;
                if (j < TOP_K && j > i) {
                    float4 bj = B4[j];
                    float aj = fmaxf(bj.z - bj.x, 0.0f) * fmaxf(bj.w - bj.y, 0.0f);
                    float xx1 = fmaxf(bi.x, bj.x), yy1 = fmaxf(bi.y, bj.y);
                    float xx2 = fminf(bi.z, bj.z), yy2 = fminf(bi.w, bj.w);
                    float inter = fmaxf(xx2 - xx1, 0.0f) * fmaxf(yy2 - yy1, 0.0f);
                    float iou = inter / (ai + aj - inter + 1e-8f);
                    sup = iou > IOU_THRESH;
                }
                u64 mask = __ballot(sup ? 1 : 0);
                if (lane == 0) { st_sc(&M[(size_t)i * 16 + w], mask); any |= mask; }
            }
            if (lane == 0) st_sc(&rflag[i], (any != 0ull) ? 1u : 0u);
        }
    } else {
        // Block 0 (excluded from IoU) pre-builds the keep bitmask from sscore
        // (ready since bar2) -> shortens the serial NMS tail after bar3.
        u32 nb = 0;
        int j0 = 4 * t;
        #pragma unroll
        for (int q = 0; q < 4; q++) {
            int j = j0 + q;
            if (j < TOP_K && sscore[j] > SCORE_THRESH) nb |= (1u << q);
        }
        sh.nms.nib[t] = nb;
        __syncthreads();
        if (t < 16) {
            u64 w = 0;
            for (int m2 = 0; m2 < 16; m2++)
                w |= ((u64)sh.nms.nib[t * 16 + m2]) << (4 * m2);
            sh.nms.keepS[t] = w;
        }
    }
    gbar(barr, 3, b, G, b == 0);             // only block 0 (S6) consumes

    // ---------- S6: greedy NMS over active rows + finalize (block 0) ----------
    if (b == 0) {
        u32 flags = 0; int cnt = 0;
        {
            int r0 = 4 * t;
            #pragma unroll
            for (int q = 0; q < 4; q++) {
                int r = r0 + q;
                if (r < TOP_K && rflag[r]) { flags |= (1u << q); cnt++; }
            }
        }
        int x = cnt;
        for (int off = 1; off < 64; off <<= 1) {
            int v = __shfl_up(x, off, 64);
            if (lane >= off) x += v;
        }
        if (lane == 63) sh.nms.wsum[wv] = (u32)x;
        __syncthreads();
        int base = 0;
        for (int w = 0; w < wv; w++) base += (int)sh.nms.wsum[w];
        int pos = base + x - cnt;
        {
            int r0 = 4 * t;
            #pragma unroll
            for (int q = 0; q < 4; q++)
                if (flags & (1u << q)) sh.nms.act[pos++] = r0 + q;
        }
        if (t == 0) {
            int na = 0;
            for (int w = 0; w < 4; w++) na += (int)sh.nms.wsum[w];
            sh.nms.nactS = na;
        }
        __syncthreads();
        int nact = sh.nms.nactS;
        int nchunks = (nact + NMS_CHUNK - 1) / NMS_CHUNK;

        // Double-buffered chunked greedy with register-prefetched mask rows.
        if (nchunks > 0) {
            int cn0 = (nact < NMS_CHUNK) ? nact : NMS_CHUNK;
            for (int i = t; i < cn0 * 16; i += 256) {
                int row = sh.nms.act[i >> 4];
                sh.nms.Ml[i] = M[(size_t)row * 16 + (i & 15)];
            }
        }
        __syncthreads();
        u64 kp = (wv == 0 && lane < 16) ? sh.nms.keepS[lane] : 0ull;
        for (int ci = 0; ci < nchunks; ci++) {
            int c0 = ci * NMS_CHUNK;
            int cn = (nact - c0 < NMS_CHUNK) ? (nact - c0) : NMS_CHUNK;
            int cur = (ci & 1) * (NMS_CHUNK * 16);
            if (ci + 1 < nchunks && t >= 64) {
                int c0n = c0 + NMS_CHUNK;
                int cnn = (nact - c0n < NMS_CHUNK) ? (nact - c0n) : NMS_CHUNK;
                int nxt = ((ci + 1) & 1) * (NMS_CHUNK * 16);
                for (int i = t - 64; i < cnn * 16; i += 192) {
                    int row = sh.nms.act[c0n + (i >> 4)];
                    sh.nms.Ml[nxt + i] = M[(size_t)row * 16 + (i & 15)];
                }
            }
            if (wv == 0) {
                u64 mreg = (lane < 16 && cn > 0) ? sh.nms.Ml[cur + lane] : 0ull;
                for (int k = 0; k < cn; k++) {
                    u64 mnx = (lane < 16 && k + 1 < cn)
                            ? sh.nms.Ml[cur + (k + 1) * 16 + lane] : 0ull;
                    int i = sh.nms.act[c0 + k];
                    u64 kw = __shfl(kp, i >> 6, 64);
                    if ((kw >> (i & 63)) & 1ull) kp &= ~mreg;
                    mreg = mnx;
                }
            }
            __syncthreads();
        }
        if (wv == 0 && lane < 16) sh.nms.keepS[lane] = kp;
        __syncthreads();

        if (t == 0) {
            int cnt2 = 0;
            for (int w = 0; w < 16 && cnt2 < MAX_DET; w++) {
                u64 kw = sh.nms.keepS[w];
                while (kw && cnt2 < MAX_DET) {
                    int bbit = __ffsll((unsigned long long)kw) - 1;
                    sh.nms.det[cnt2++] = w * 64 + bbit;
                    kw &= kw - 1;
                }
            }
            for (; cnt2 < MAX_DET; cnt2++) sh.nms.det[cnt2] = -1;
        }
        __syncthreads();
        if (t < MAX_DET) {
            int i = sh.nms.det[t];
            if (i >= 0) {
                u32 a = sidx[i];
                const float* p = cls + (size_t)a * C;
                float best = -1e30f; int bc = 0;
                if (C == 80) {
                    #pragma unroll
                    for (int c4 = 0; c4 < 20; c4++) {
                        float4 v = *(const float4*)(p + c4 * 4);
                        if (v.x > best) { best = v.x; bc = c4 * 4; }
                        if (v.y > best) { best = v.y; bc = c4 * 4 + 1; }
                        if (v.z > best) { best = v.z; bc = c4 * 4 + 2; }
                        if (v.w > best) { best = v.w; bc = c4 * 4 + 3; }
                    }
                } else {
                    best = p[0]; bc = 0;
                    for (int c = 1; c < C; c++) {
                        float v = p[c];
                        if (v > best) { best = v; bc = c; }
                    }
                }
                out[t] = best;
                out[MAX_DET + t] = (float)bc;
                out[2 * MAX_DET + t * 4 + 0] = cbox[i * 4 + 0];
                out[2 * MAX_DET + t * 4 + 1] = cbox[i * 4 + 1];
                out[2 * MAX_DET + t * 4 + 2] = cbox[i * 4 + 2];
                out[2 * MAX_DET + t * 4 + 3] = cbox[i * 4 + 3];
            } else {
                out[t] = 0.0f;
                out[MAX_DET + t] = -1.0f;
                out[2 * MAX_DET + t * 4 + 0] = 0.0f;
                out[2 * MAX_DET + t * 4 + 1] = 0.0f;
                out[2 * MAX_DET + t * 4 + 2] = 0.0f;
                out[2 * MAX_DET + t * 4 + 3] = 0.0f;
            }
        }
    }
}

extern "C" void kernel_launch(void* const* d_in, const int* in_sizes, int n_in,
                              void* d_out, int out_size, void* d_ws, size_t ws_size,
                              hipStream_t stream) {
    (void)n_in; (void)out_size; (void)ws_size;
    const float* cls     = (const float*)d_in[0];
    const float* regs    = (const float*)d_in[1];
    const float* anchors = (const float*)d_in[2];
    const int*   pH      = (const int*)d_in[3];
    const int*   pW      = (const int*)d_in[4];
    int A = in_sizes[1] / 4;
    int C = in_sizes[0] / A;

    // grid = 2 blocks/CU, capped at 512 (flag-row capacity):
    // co-residency guaranteed (37.6KB LDS -> 2 blocks/CU, launch_bounds(256,2)).
    static int nCU = 0;
    if (nCU <= 0) {
        int dev = 0;
        hipGetDevice(&dev);
        hipDeviceGetAttribute(&nCU, hipDeviceAttributeMultiprocessorCount, dev);
        if (nCU <= 0) nCU = 256;
    }
    int G = 2 * nCU;
    if (G > 512) G = 512;
    if (G < 8) G = 8;

    char* ws = (char*)d_ws;
    // Zero hist + state + barrier flags in one memset; the fill dispatch's
    // completion makes the zeros coherence-point visible.
    hipMemsetAsync(ws, 0, MEMSET_LEN, stream);
    mega<<<dim3(G), dim3(256), 0, stream>>>(cls, regs, anchors, pH, pW, A, C,
                                            ws, (float*)d_out);
}